// Round 3
// baseline (2089.426 us; speedup 1.0000x reference)
//
#include <hip/hip_runtime.h>

#define N_NODES 50000
#define MP 50048            // row-tile padding (128-multiple) for GEMM grids

typedef short short8 __attribute__((ext_vector_type(8)));
typedef float floatx4 __attribute__((ext_vector_type(4)));

__device__ __forceinline__ float bf2f(ushort u) {
    union { unsigned int i; float f; } x; x.i = ((unsigned int)u) << 16; return x.f;
}
__device__ __forceinline__ ushort f2bf(float f) {
    union { float f; unsigned int i; } x; x.f = f;
    unsigned int r = x.i + 0x7FFFu + ((x.i >> 16) & 1u);
    return (ushort)(r >> 16);
}

// ---------- small utility kernels ----------
__global__ __launch_bounds__(256) void deg_count_kernel(const int* __restrict__ dst,
                                                        float* __restrict__ deg, int E) {
    int i = blockIdx.x * 256 + threadIdx.x;
    if (i < E) atomicAdd(&deg[dst[i]], 1.0f);
}
__global__ __launch_bounds__(256) void invsqrt_kernel(float* __restrict__ deg, int n) {
    int i = blockIdx.x * 256 + threadIdx.x;
    if (i < n) deg[i] = rsqrtf(deg[i] + 1.0f);
}
// f32 -> bf16 elementwise
__global__ __launch_bounds__(256) void f2b_kernel(const float* __restrict__ in,
                                                  ushort* __restrict__ out, int n) {
    int i = blockIdx.x * 256 + threadIdx.x;
    if (i < n) out[i] = f2bf(in[i]);
}
// Wt[n*K+k] = bf16(W[k*N+n])   (f32 -> bf16 transpose)
__global__ __launch_bounds__(256) void transpose_kernel(const float* __restrict__ W,
                                                        ushort* __restrict__ Wt, int K, int N) {
    int idx = blockIdx.x * 256 + threadIdx.x;
    if (idx < K * N) {
        int k = idx / N, n = idx % N;
        Wt[n * K + k] = f2bf(W[idx]);
    }
}

// ---------- bf16 MFMA GEMM:  C[M,N] = A[M,K] @ Bt[N,K]^T  (m97-style 128x128 tile) ----------
__global__ __launch_bounds__(256) void gemm_kernel(
    const ushort* __restrict__ A, const ushort* __restrict__ Bt,
    ushort* __restrict__ C, const float* __restrict__ bias,
    int M, int K, int N, int do_relu)
{
    __shared__ __align__(16) ushort Alds[128 * 32];
    __shared__ __align__(16) ushort Blds[128 * 32];
    const int t = threadIdx.x;
    const int w = t >> 6, l = t & 63;
    const int m0 = blockIdx.x * 128;
    const int n0 = blockIdx.y * 128;
    const int wr = (w >> 1) * 64, wc = (w & 1) * 64;
    const int lhi = l >> 4, llo = l & 15;

    floatx4 acc[4][4] = {};

    const int nkt = K >> 5;
    for (int kt = 0; kt < nkt; ++kt) {
        const int k0 = kt << 5;
#pragma unroll
        for (int i = 0; i < 2; ++i) {
            int s = i * 256 + t;
            int row = s >> 2, seg = s & 3;
            int gr = m0 + row; gr = gr < M ? gr : M - 1;   // clamp: never read past row M-1
            const ushort* ga = A + (size_t)gr * K + (k0 + seg * 8);
            __builtin_amdgcn_global_load_lds(
                (const __attribute__((address_space(1))) void*)ga,
                (__attribute__((address_space(3))) void*)(Alds + (size_t)(i * 256 + w * 64) * 8),
                16, 0, 0);
            const ushort* gb = Bt + (size_t)(n0 + row) * K + (k0 + seg * 8);
            __builtin_amdgcn_global_load_lds(
                (const __attribute__((address_space(1))) void*)gb,
                (__attribute__((address_space(3))) void*)(Blds + (size_t)(i * 256 + w * 64) * 8),
                16, 0, 0);
        }
        __syncthreads();
        short8 av[4], bv[4];
#pragma unroll
        for (int m = 0; m < 4; ++m)
            av[m] = *reinterpret_cast<const short8*>(&Alds[(wr + m * 16 + llo) * 32 + lhi * 8]);
#pragma unroll
        for (int n = 0; n < 4; ++n)
            bv[n] = *reinterpret_cast<const short8*>(&Blds[(wc + n * 16 + llo) * 32 + lhi * 8]);
#pragma unroll
        for (int m = 0; m < 4; ++m)
#pragma unroll
            for (int n = 0; n < 4; ++n)
                acc[m][n] = __builtin_amdgcn_mfma_f32_16x16x32_bf16(av[m], bv[n], acc[m][n], 0, 0, 0);
        __syncthreads();
    }

    const int lr = lhi * 4;
#pragma unroll
    for (int m = 0; m < 4; ++m) {
#pragma unroll
        for (int n = 0; n < 4; ++n) {
            int gcol = n0 + wc + n * 16 + llo;
            float badd = bias ? bias[gcol] : 0.0f;
#pragma unroll
            for (int j = 0; j < 4; ++j) {
                int grow = m0 + wr + m * 16 + lr + j;
                if (grow < M) {                          // guard: C buffers are NOT row-padded
                    float v = acc[m][n][j] + badd;
                    if (do_relu) v = fmaxf(v, 0.0f);
                    C[(size_t)grow * N + gcol] = f2bf(v);
                }
            }
        }
    }
}

// ---------- edge scatter (256-ch slice): agg[dst] += h[src, slice] * invs[src]*invs[dst] ----------
__global__ __launch_bounds__(256) void scatter_kernel(
    const int* __restrict__ srcI, const int* __restrict__ dstI,
    const ushort* __restrict__ h, int ldh,
    const float* __restrict__ invs, float* __restrict__ agg, int E)
{
    const int w = threadIdx.x >> 6, l = threadIdx.x & 63;
    const int e = blockIdx.x * 4 + w;
    if (e >= E) return;
    const int s = srcI[e], d = dstI[e];
    const float coef = invs[s] * invs[d];
    const ushort* hr = h + (size_t)s * ldh;
    float* ar = agg + (size_t)d * 256;
#pragma unroll
    for (int k = 0; k < 4; ++k) {
        int c = l + k * 64;
        atomicAdd(&ar[c], bf2f(hr[c]) * coef);
    }
}

// ---------- epilogue (256-ch slice): v = [relu]( agg + h*inv^2 [+ bias] ) ----------
// WF: write f32 out (stride 256; may alias agg in-place). WB: write bf16 out (stride ld).
template<bool RELU, bool BIAS, bool WF, bool WB>
__global__ __launch_bounds__(256) void epi_kernel(
    const float* __restrict__ agg, const ushort* __restrict__ h, int ld,
    const float* __restrict__ invs, const float* __restrict__ bias,
    float* __restrict__ outF, ushort* __restrict__ outB)
{
    const int idx = blockIdx.x * 256 + threadIdx.x;   // grid = 50000 blocks
    const int row = idx >> 8;
    const int c = idx & 255;
    const size_t ha = (size_t)row * ld + c;
    const float iv = invs[row];
    float v = agg[idx] + bf2f(h[ha]) * iv * iv;
    if (BIAS) v += bias[c];
    if (RELU) v = fmaxf(v, 0.0f);
    if (WF) outF[idx] = v;
    if (WB) outB[ha] = f2bf(v);
}

extern "C" void kernel_launch(void* const* d_in, const int* in_sizes, int n_in,
                              void* d_out, int out_size, void* d_ws, size_t ws_size,
                              hipStream_t stream)
{
    const float* x  = (const float*)d_in[0];
    const int* ei1  = (const int*)d_in[1];
    const int* ei2  = (const int*)d_in[2];
    const float* W1 = (const float*)d_in[3];
    const float* b1 = (const float*)d_in[4];
    const float* W2 = (const float*)d_in[5];
    const float* b2 = (const float*)d_in[6];
    const float* W3 = (const float*)d_in[7];
    const float* b3 = (const float*)d_in[8];
    const float* W4 = (const float*)d_in[9];
    const float* b4 = (const float*)d_in[10];
    float* z   = (float*)d_out;                        // [50000,256] f32
    float* z_g = z + (size_t)N_NODES * 256;            // [50000,256] f32

    const int E1 = in_sizes[1] / 2, E2 = in_sizes[2] / 2;
    const int* src1 = ei1;  const int* dst1 = ei1 + E1;
    const int* src2 = ei2;  const int* dst2 = ei2 + E2;

    // ---- aliases on d_out (both regions are 51.2e6 B) ----
    ushort* Xb   = (ushort*)z_g;   // bf16 x copy [50000,512]; dead after GEMM1
    float*  AGG1 = z;              // f32 accumulator; epi L2 converts it to z in place
    float*  AGG2 = z_g;            // f32 accumulator (after Xb dead); epi final -> z_g in place

    // ---- workspace (~79 MB) ----
    char* ws = (char*)d_ws;
    size_t off = 0;
    auto alloc = [&](size_t bytes) { void* p = ws + off; off += (bytes + 255) & ~(size_t)255; return p; };
    ushort* R0   = (ushort*)alloc((size_t)N_NODES * 512 * 2);  // bf16 [50000,512]
    ushort* R1   = (ushort*)alloc((size_t)N_NODES * 256 * 2);  // bf16 [50000,256]
    float*  inv1 = (float*) alloc((size_t)N_NODES * 4);
    float*  inv2 = (float*) alloc((size_t)N_NODES * 4);
    ushort* Wt1  = (ushort*)alloc(512 * 512 * 2);
    ushort* Wt2  = (ushort*)alloc(256 * 512 * 2);
    ushort* Wt3  = (ushort*)alloc(512 * 256 * 2);
    ushort* Wt4  = (ushort*)alloc(256 * 512 * 2);

    const dim3 blk(256);
    const int MT = MP / 128;                 // 391 row tiles
    const size_t aggB = (size_t)N_NODES * 256 * 4;

    // degree -> inv-sqrt (with self-loop +1)
    hipMemsetAsync(inv1, 0, (size_t)N_NODES * 4, stream);
    hipMemsetAsync(inv2, 0, (size_t)N_NODES * 4, stream);
    deg_count_kernel<<<(E1 + 255) / 256, blk, 0, stream>>>(dst1, inv1, E1);
    deg_count_kernel<<<(E2 + 255) / 256, blk, 0, stream>>>(dst2, inv2, E2);
    invsqrt_kernel<<<(N_NODES + 255) / 256, blk, 0, stream>>>(inv1, N_NODES);
    invsqrt_kernel<<<(N_NODES + 255) / 256, blk, 0, stream>>>(inv2, N_NODES);

    // weights: W[K,N] f32 -> Wt[N,K] bf16 ; x -> bf16
    transpose_kernel<<<(512 * 512 + 255) / 256, blk, 0, stream>>>(W1, Wt1, 512, 512);
    transpose_kernel<<<(512 * 256 + 255) / 256, blk, 0, stream>>>(W2, Wt2, 512, 256);
    transpose_kernel<<<(256 * 512 + 255) / 256, blk, 0, stream>>>(W3, Wt3, 256, 512);
    transpose_kernel<<<(512 * 256 + 255) / 256, blk, 0, stream>>>(W4, Wt4, 512, 256);
    f2b_kernel<<<(N_NODES * 512 + 255) / 256, blk, 0, stream>>>(x, Xb, N_NODES * 512);

    // ---- encoder 1, layer 1: h1 = x@W1 -> R0 ; a1 = relu(prop1(h1)+b1) in-place (2 col-halves) ----
    gemm_kernel<<<dim3(MT, 4), blk, 0, stream>>>(Xb, Wt1, R0, nullptr, N_NODES, 512, 512, 0);
    for (int half = 0; half < 2; ++half) {
        ushort* hs = R0 + half * 256;
        hipMemsetAsync(AGG1, 0, aggB, stream);
        scatter_kernel<<<(E1 + 3) / 4, blk, 0, stream>>>(src1, dst1, hs, 512, inv1, AGG1, E1);
        epi_kernel<true, true, false, true><<<N_NODES, blk, 0, stream>>>(
            AGG1, hs, 512, inv1, b1 + half * 256, nullptr, hs);
    }

    // ---- encoder 1, layer 2: h2 = a1@W2 -> R1 ; z = relu(prop1(h2)+b2) (f32 in-place over AGG1) ----
    gemm_kernel<<<dim3(MT, 2), blk, 0, stream>>>(R0, Wt2, R1, nullptr, N_NODES, 512, 256, 0);
    hipMemsetAsync(AGG1, 0, aggB, stream);
    scatter_kernel<<<(E1 + 3) / 4, blk, 0, stream>>>(src1, dst1, R1, 256, inv1, AGG1, E1);
    epi_kernel<true, true, true, true><<<N_NODES, blk, 0, stream>>>(
        AGG1, R1, 256, inv1, b2, z, R0);               // z f32 + bf16 copy Zb -> R0

    // ---- encoder 2, layer 1 (propagate-first): pz = prop2(z) -> R1 ; a3 = relu(pz@W3+b3) -> R0 ----
    hipMemsetAsync(AGG2, 0, aggB, stream);             // Xb is dead from here
    scatter_kernel<<<(E2 + 3) / 4, blk, 0, stream>>>(src2, dst2, R0, 256, inv2, AGG2, E2);
    epi_kernel<false, false, false, true><<<N_NODES, blk, 0, stream>>>(
        AGG2, R0, 256, inv2, nullptr, nullptr, R1);    // pz bf16 -> R1
    gemm_kernel<<<dim3(MT, 4), blk, 0, stream>>>(R1, Wt3, R0, b3, N_NODES, 256, 512, 1);

    // ---- encoder 2, layer 2: h4 = a3@W4 -> R1 ; z_g = relu(prop2(h4)+b4) (f32 in-place over AGG2) ----
    gemm_kernel<<<dim3(MT, 2), blk, 0, stream>>>(R0, Wt4, R1, nullptr, N_NODES, 512, 256, 0);
    hipMemsetAsync(AGG2, 0, aggB, stream);
    scatter_kernel<<<(E2 + 3) / 4, blk, 0, stream>>>(src2, dst2, R1, 256, inv2, AGG2, E2);
    epi_kernel<true, true, true, false><<<N_NODES, blk, 0, stream>>>(
        AGG2, R1, 256, inv2, b4, z_g, nullptr);
}

// Round 4
// 870.349 us; speedup vs baseline: 2.4007x; 2.4007x over previous
//
#include <hip/hip_runtime.h>

#define N_NODES 50000
#define MP 50048            // row-tile padding (128-multiple) for GEMM grids

typedef short short8 __attribute__((ext_vector_type(8)));
typedef float floatx4 __attribute__((ext_vector_type(4)));
typedef ushort u16x4 __attribute__((ext_vector_type(4)));
typedef ushort u16x8 __attribute__((ext_vector_type(8)));
typedef float f32x4 __attribute__((ext_vector_type(4)));

__device__ __forceinline__ float bf2f(ushort u) {
    union { unsigned int i; float f; } x; x.i = ((unsigned int)u) << 16; return x.f;
}
__device__ __forceinline__ ushort f2bf(float f) {
    union { float f; unsigned int i; } x; x.f = f;
    unsigned int r = x.i + 0x7FFFu + ((x.i >> 16) & 1u);
    return (ushort)(r >> 16);
}

// ---------- CSR build ----------
__global__ __launch_bounds__(256) void deg_int_kernel(const int* __restrict__ dst,
                                                      int* __restrict__ deg, int E) {
    int i = blockIdx.x * 256 + threadIdx.x;
    if (i < E) atomicAdd(&deg[dst[i]], 1);
}
__global__ __launch_bounds__(256) void inv_from_deg(const int* __restrict__ deg,
                                                    float* __restrict__ inv, int n) {
    int i = blockIdx.x * 256 + threadIdx.x;
    if (i < n) inv[i] = rsqrtf((float)deg[i] + 1.0f);
}
// exclusive scan of deg[0..n) -> row_ptr[0..n], plus cursor copy
__global__ __launch_bounds__(1024) void scan_kernel(const int* __restrict__ deg,
                                                    int* __restrict__ row_ptr,
                                                    int* __restrict__ cursor, int n) {
    __shared__ int part[1024];
    const int t = threadIdx.x;
    const int chunk = (n + 1023) / 1024;
    const int lo = t * chunk, hi = min(lo + chunk, n);
    int s = 0;
    for (int i = lo; i < hi; ++i) s += deg[i];
    part[t] = s;
    __syncthreads();
    for (int d = 1; d < 1024; d <<= 1) {
        int v = (t >= d) ? part[t - d] : 0;
        __syncthreads();
        part[t] += v;
        __syncthreads();
    }
    int base = (t > 0) ? part[t - 1] : 0;
    for (int i = lo; i < hi; ++i) { row_ptr[i] = base; cursor[i] = base; base += deg[i]; }
    if (hi == n) row_ptr[n] = base;
}
__global__ __launch_bounds__(256) void fill_adj_kernel(const int* __restrict__ src,
                                                       const int* __restrict__ dst,
                                                       int* __restrict__ cursor,
                                                       int* __restrict__ adj, int E) {
    int i = blockIdx.x * 256 + threadIdx.x;
    if (i < E) {
        int pos = atomicAdd(&cursor[dst[i]], 1);
        adj[pos] = src[i];
    }
}

// ---------- weight prep ----------
__global__ __launch_bounds__(256) void f2b_kernel(const float* __restrict__ in,
                                                  ushort* __restrict__ out, int n) {
    int i = blockIdx.x * 256 + threadIdx.x;
    if (i < n) out[i] = f2bf(in[i]);
}
__global__ __launch_bounds__(256) void transpose_kernel(const float* __restrict__ W,
                                                        ushort* __restrict__ Wt, int K, int N) {
    int idx = blockIdx.x * 256 + threadIdx.x;
    if (idx < K * N) {
        int k = idx / N, n = idx % N;
        Wt[n * K + k] = f2bf(W[idx]);
    }
}

// ---------- bf16 MFMA GEMM:  C[M,N] = A[M,K] @ Bt[N,K]^T  (128x128 tile) ----------
__global__ __launch_bounds__(256) void gemm_kernel(
    const ushort* __restrict__ A, const ushort* __restrict__ Bt,
    ushort* __restrict__ C, const float* __restrict__ bias,
    int M, int K, int N, int do_relu)
{
    __shared__ __align__(16) ushort Alds[128 * 32];
    __shared__ __align__(16) ushort Blds[128 * 32];
    const int t = threadIdx.x;
    const int w = t >> 6, l = t & 63;
    const int m0 = blockIdx.x * 128;
    const int n0 = blockIdx.y * 128;
    const int wr = (w >> 1) * 64, wc = (w & 1) * 64;
    const int lhi = l >> 4, llo = l & 15;

    floatx4 acc[4][4] = {};

    const int nkt = K >> 5;
    for (int kt = 0; kt < nkt; ++kt) {
        const int k0 = kt << 5;
#pragma unroll
        for (int i = 0; i < 2; ++i) {
            int s = i * 256 + t;
            int row = s >> 2, seg = s & 3;
            int gr = m0 + row; gr = gr < M ? gr : M - 1;   // clamp: never read past row M-1
            const ushort* ga = A + (size_t)gr * K + (k0 + seg * 8);
            __builtin_amdgcn_global_load_lds(
                (const __attribute__((address_space(1))) void*)ga,
                (__attribute__((address_space(3))) void*)(Alds + (size_t)(i * 256 + w * 64) * 8),
                16, 0, 0);
            const ushort* gb = Bt + (size_t)(n0 + row) * K + (k0 + seg * 8);
            __builtin_amdgcn_global_load_lds(
                (const __attribute__((address_space(1))) void*)gb,
                (__attribute__((address_space(3))) void*)(Blds + (size_t)(i * 256 + w * 64) * 8),
                16, 0, 0);
        }
        __syncthreads();
        short8 av[4], bv[4];
#pragma unroll
        for (int m = 0; m < 4; ++m)
            av[m] = *reinterpret_cast<const short8*>(&Alds[(wr + m * 16 + llo) * 32 + lhi * 8]);
#pragma unroll
        for (int n = 0; n < 4; ++n)
            bv[n] = *reinterpret_cast<const short8*>(&Blds[(wc + n * 16 + llo) * 32 + lhi * 8]);
#pragma unroll
        for (int m = 0; m < 4; ++m)
#pragma unroll
            for (int n = 0; n < 4; ++n)
                acc[m][n] = __builtin_amdgcn_mfma_f32_16x16x32_bf16(av[m], bv[n], acc[m][n], 0, 0, 0);
        __syncthreads();
    }

    const int lr = lhi * 4;
#pragma unroll
    for (int m = 0; m < 4; ++m) {
#pragma unroll
        for (int n = 0; n < 4; ++n) {
            int gcol = n0 + wc + n * 16 + llo;
            float badd = bias ? bias[gcol] : 0.0f;
#pragma unroll
            for (int j = 0; j < 4; ++j) {
                int grow = m0 + wr + m * 16 + lr + j;
                if (grow < M) {
                    float v = acc[m][n][j] + badd;
                    if (do_relu) v = fmaxf(v, 0.0f);
                    C[(size_t)grow * N + gcol] = f2bf(v);
                }
            }
        }
    }
}

// ---------- CSR gather + fused epilogue ----------
// out[node] = [relu]( sum_{s in adj(node)} h[s]*inv[s]*inv[node] + h[node]*inv[node]^2 [+ bias] )
// One wave per node; lane owns V=C/64 consecutive channels.
template<int C, bool RELU, bool BIAS, bool WF, bool WB>
__global__ __launch_bounds__(256) void gather_kernel(
    const int* __restrict__ row_ptr, const int* __restrict__ adj,
    const ushort* __restrict__ h, const float* __restrict__ invs,
    const float* __restrict__ bias,
    float* __restrict__ outF, ushort* __restrict__ outB)
{
    constexpr int V = C / 64;
    const int wv = threadIdx.x >> 6, l = threadIdx.x & 63;
    const int node = blockIdx.x * 4 + wv;
    if (node >= N_NODES) return;
    const int c0 = l * V;
    const int beg = row_ptr[node], end = row_ptr[node + 1];
    const float invd = invs[node];

    float acc[V];
#pragma unroll
    for (int k = 0; k < V; ++k) acc[k] = 0.0f;

    for (int e = beg; e < end; ++e) {
        const int s = adj[e];
        const float coef = invs[s] * invd;
        const ushort* hp = h + (size_t)s * C + c0;
        if constexpr (V == 4) {
            u16x4 hv = *reinterpret_cast<const u16x4*>(hp);
#pragma unroll
            for (int k = 0; k < 4; ++k) acc[k] += bf2f(hv[k]) * coef;
        } else {
            u16x8 hv = *reinterpret_cast<const u16x8*>(hp);
#pragma unroll
            for (int k = 0; k < 8; ++k) acc[k] += bf2f(hv[k]) * coef;
        }
    }
    {   // self-loop
        const float coef = invd * invd;
        const ushort* hp = h + (size_t)node * C + c0;
        if constexpr (V == 4) {
            u16x4 hv = *reinterpret_cast<const u16x4*>(hp);
#pragma unroll
            for (int k = 0; k < 4; ++k) acc[k] += bf2f(hv[k]) * coef;
        } else {
            u16x8 hv = *reinterpret_cast<const u16x8*>(hp);
#pragma unroll
            for (int k = 0; k < 8; ++k) acc[k] += bf2f(hv[k]) * coef;
        }
    }
#pragma unroll
    for (int k = 0; k < V; ++k) {
        float v = acc[k];
        if (BIAS) v += bias[c0 + k];
        if (RELU) v = fmaxf(v, 0.0f);
        acc[k] = v;
    }
    if (WF) {
        float* op = outF + (size_t)node * C + c0;
#pragma unroll
        for (int k = 0; k < V; k += 4)
            *reinterpret_cast<f32x4*>(op + k) = *reinterpret_cast<f32x4*>(&acc[k]);
    }
    if (WB) {
        ushort* op = outB + (size_t)node * C + c0;
        if constexpr (V == 4) {
            u16x4 o; 
#pragma unroll
            for (int k = 0; k < 4; ++k) o[k] = f2bf(acc[k]);
            *reinterpret_cast<u16x4*>(op) = o;
        } else {
            u16x8 o;
#pragma unroll
            for (int k = 0; k < 8; ++k) o[k] = f2bf(acc[k]);
            *reinterpret_cast<u16x8*>(op) = o;
        }
    }
}

extern "C" void kernel_launch(void* const* d_in, const int* in_sizes, int n_in,
                              void* d_out, int out_size, void* d_ws, size_t ws_size,
                              hipStream_t stream)
{
    const float* x  = (const float*)d_in[0];
    const int* ei1  = (const int*)d_in[1];
    const int* ei2  = (const int*)d_in[2];
    const float* W1 = (const float*)d_in[3];
    const float* b1 = (const float*)d_in[4];
    const float* W2 = (const float*)d_in[5];
    const float* b2 = (const float*)d_in[6];
    const float* W3 = (const float*)d_in[7];
    const float* b3 = (const float*)d_in[8];
    const float* W4 = (const float*)d_in[9];
    const float* b4 = (const float*)d_in[10];
    float* z   = (float*)d_out;                        // [50000,256] f32
    float* z_g = z + (size_t)N_NODES * 256;            // [50000,256] f32

    const int E1 = in_sizes[1] / 2, E2 = in_sizes[2] / 2;
    const int* src1 = ei1;  const int* dst1 = ei1 + E1;
    const int* src2 = ei2;  const int* dst2 = ei2 + E2;

    // ---- aliases on d_out (each half = 51.2 MB = [50000,512] bf16 exactly) ----
    ushort* Xb = (ushort*)z;      // bf16 x; dead after GEMM1; then z f32 overwrites
    ushort* R1 = (ushort*)z_g;    // 512-wide bf16 ping buffer; final gather writes z_g f32 over it

    // ---- workspace (~57 MB) ----
    char* ws = (char*)d_ws;
    size_t off = 0;
    auto alloc = [&](size_t bytes) { void* p = ws + off; off += (bytes + 255) & ~(size_t)255; return p; };
    ushort* R0   = (ushort*)alloc((size_t)N_NODES * 512 * 2);
    float*  inv1 = (float*) alloc((size_t)N_NODES * 4);
    float*  inv2 = (float*) alloc((size_t)N_NODES * 4);
    int*    deg1 = (int*)   alloc((size_t)N_NODES * 4);
    int*    deg2 = (int*)   alloc((size_t)N_NODES * 4);
    int*    rp1  = (int*)   alloc((size_t)(N_NODES + 1) * 4);
    int*    rp2  = (int*)   alloc((size_t)(N_NODES + 1) * 4);
    int*    cur1 = (int*)   alloc((size_t)N_NODES * 4);
    int*    cur2 = (int*)   alloc((size_t)N_NODES * 4);
    int*    adj1 = (int*)   alloc((size_t)E1 * 4);
    int*    adj2 = (int*)   alloc((size_t)E2 * 4);
    ushort* Wt1  = (ushort*)alloc(512 * 512 * 2);
    ushort* Wt2  = (ushort*)alloc(256 * 512 * 2);
    ushort* Wt3  = (ushort*)alloc(512 * 256 * 2);
    ushort* Wt4  = (ushort*)alloc(256 * 512 * 2);

    const dim3 blk(256);
    const int MT = MP / 128;                 // 391 row tiles
    const int GB = (N_NODES + 3) / 4;        // gather blocks (4 waves each)

    // ---- CSR build for both edge sets ----
    hipMemsetAsync(deg1, 0, (size_t)N_NODES * 4, stream);
    hipMemsetAsync(deg2, 0, (size_t)N_NODES * 4, stream);
    deg_int_kernel<<<(E1 + 255) / 256, blk, 0, stream>>>(dst1, deg1, E1);
    deg_int_kernel<<<(E2 + 255) / 256, blk, 0, stream>>>(dst2, deg2, E2);
    inv_from_deg<<<(N_NODES + 255) / 256, blk, 0, stream>>>(deg1, inv1, N_NODES);
    inv_from_deg<<<(N_NODES + 255) / 256, blk, 0, stream>>>(deg2, inv2, N_NODES);
    scan_kernel<<<1, 1024, 0, stream>>>(deg1, rp1, cur1, N_NODES);
    scan_kernel<<<1, 1024, 0, stream>>>(deg2, rp2, cur2, N_NODES);
    fill_adj_kernel<<<(E1 + 255) / 256, blk, 0, stream>>>(src1, dst1, cur1, adj1, E1);
    fill_adj_kernel<<<(E2 + 255) / 256, blk, 0, stream>>>(src2, dst2, cur2, adj2, E2);

    // ---- weight prep + x -> bf16 ----
    transpose_kernel<<<(512 * 512 + 255) / 256, blk, 0, stream>>>(W1, Wt1, 512, 512);
    transpose_kernel<<<(512 * 256 + 255) / 256, blk, 0, stream>>>(W2, Wt2, 512, 256);
    transpose_kernel<<<(256 * 512 + 255) / 256, blk, 0, stream>>>(W3, Wt3, 256, 512);
    transpose_kernel<<<(512 * 256 + 255) / 256, blk, 0, stream>>>(W4, Wt4, 512, 256);
    f2b_kernel<<<(N_NODES * 512 + 255) / 256, blk, 0, stream>>>(x, Xb, N_NODES * 512);

    // ---- encoder 1, layer 1: h1 = x@W1 -> R0 ; a1 = relu(P1(h1)+b1) -> R1 (bf16) ----
    gemm_kernel<<<dim3(MT, 4), blk, 0, stream>>>(Xb, Wt1, R0, nullptr, N_NODES, 512, 512, 0);
    gather_kernel<512, true, true, false, true><<<GB, blk, 0, stream>>>(
        rp1, adj1, R0, inv1, b1, nullptr, R1);

    // ---- encoder 1, layer 2: h2 = a1@W2 -> R0(256) ; z = relu(P1(h2)+b2) -> z f32 + zb -> R1 ----
    gemm_kernel<<<dim3(MT, 2), blk, 0, stream>>>(R1, Wt2, R0, nullptr, N_NODES, 512, 256, 0);
    gather_kernel<256, true, true, true, true><<<GB, blk, 0, stream>>>(
        rp1, adj1, R0, inv1, b2, z, R1);

    // ---- encoder 2, layer 1 (propagate-first): pz = P2(zb) -> R0(256) ; a3 = relu(pz@W3+b3) -> R1 ----
    gather_kernel<256, false, false, false, true><<<GB, blk, 0, stream>>>(
        rp2, adj2, R1, inv2, nullptr, nullptr, R0);
    gemm_kernel<<<dim3(MT, 4), blk, 0, stream>>>(R0, Wt3, R1, b3, N_NODES, 256, 512, 1);

    // ---- encoder 2, layer 2: h4 = a3@W4 -> R0(256) ; z_g = relu(P2(h4)+b4) -> z_g f32 ----
    gemm_kernel<<<dim3(MT, 2), blk, 0, stream>>>(R1, Wt4, R0, nullptr, N_NODES, 512, 256, 0);
    gather_kernel<256, true, true, true, false><<<GB, blk, 0, stream>>>(
        rp2, adj2, R0, inv2, b4, z_g, nullptr);
}

// Round 5
// 670.835 us; speedup vs baseline: 3.1147x; 1.2974x over previous
//
#include <hip/hip_runtime.h>

#define N_NODES 50000
#define MP 50048            // row-tile padding (128-multiple) for GEMM grids

typedef short short8 __attribute__((ext_vector_type(8)));
typedef float floatx4 __attribute__((ext_vector_type(4)));
typedef ushort u16x4 __attribute__((ext_vector_type(4)));
typedef ushort u16x8 __attribute__((ext_vector_type(8)));
typedef float f32x4 __attribute__((ext_vector_type(4)));

__device__ __forceinline__ float bf2f(ushort u) {
    union { unsigned int i; float f; } x; x.i = ((unsigned int)u) << 16; return x.f;
}
__device__ __forceinline__ ushort f2bf(float f) {
    union { float f; unsigned int i; } x; x.f = f;
    unsigned int r = x.i + 0x7FFFu + ((x.i >> 16) & 1u);
    return (ushort)(r >> 16);
}

// ---------- CSR build ----------
__global__ __launch_bounds__(256) void deg_int_kernel(const int* __restrict__ dst,
                                                      int* __restrict__ deg, int E) {
    int i = blockIdx.x * 256 + threadIdx.x;
    if (i < E) atomicAdd(&deg[dst[i]], 1);
}
__global__ __launch_bounds__(256) void inv_from_deg(const int* __restrict__ deg,
                                                    float* __restrict__ inv, int n) {
    int i = blockIdx.x * 256 + threadIdx.x;
    if (i < n) inv[i] = rsqrtf((float)deg[i] + 1.0f);
}

// ---- hierarchical exclusive scan (n <= 256*256) ----
// stage 1: per-block local exclusive scan -> row_ptr (local), block sum -> bsum[b]
__global__ __launch_bounds__(256) void scan1_kernel(const int* __restrict__ deg,
                                                    int* __restrict__ pre,
                                                    int* __restrict__ bsum, int n) {
    __shared__ int tmp[256];
    const int t = threadIdx.x;
    const int i = blockIdx.x * 256 + t;
    const int v = (i < n) ? deg[i] : 0;
    tmp[t] = v;
    __syncthreads();
#pragma unroll
    for (int d = 1; d < 256; d <<= 1) {
        int u = (t >= d) ? tmp[t - d] : 0;
        __syncthreads();
        tmp[t] += u;
        __syncthreads();
    }
    if (i < n) pre[i] = tmp[t] - v;           // exclusive within block
    if (t == 255) bsum[blockIdx.x] = tmp[255];
}
// stage 2: one block scans the block sums (nb <= 256) -> exclusive offsets; total -> row_ptr[n]
__global__ __launch_bounds__(256) void scan2_kernel(int* __restrict__ bsum, int nb,
                                                    int* __restrict__ row_ptr_n) {
    __shared__ int tmp[256];
    const int t = threadIdx.x;
    const int v = (t < nb) ? bsum[t] : 0;
    tmp[t] = v;
    __syncthreads();
#pragma unroll
    for (int d = 1; d < 256; d <<= 1) {
        int u = (t >= d) ? tmp[t - d] : 0;
        __syncthreads();
        tmp[t] += u;
        __syncthreads();
    }
    if (t < nb) bsum[t] = tmp[t] - v;         // exclusive block offsets
    if (t == 255) *row_ptr_n = tmp[255];      // grand total
}
// stage 3: add block offset; write final row_ptr and cursor copy
__global__ __launch_bounds__(256) void scan3_kernel(const int* __restrict__ pre,
                                                    const int* __restrict__ bsum,
                                                    int* __restrict__ row_ptr,
                                                    int* __restrict__ cursor, int n) {
    const int i = blockIdx.x * 256 + threadIdx.x;
    if (i < n) {
        int v = pre[i] + bsum[blockIdx.x];
        row_ptr[i] = v;
        cursor[i] = v;
    }
}
__global__ __launch_bounds__(256) void fill_adj_kernel(const int* __restrict__ src,
                                                       const int* __restrict__ dst,
                                                       int* __restrict__ cursor,
                                                       int* __restrict__ adj, int E) {
    int i = blockIdx.x * 256 + threadIdx.x;
    if (i < E) {
        int pos = atomicAdd(&cursor[dst[i]], 1);
        adj[pos] = src[i];
    }
}

// ---------- weight prep ----------
__global__ __launch_bounds__(256) void f2b_kernel(const float* __restrict__ in,
                                                  ushort* __restrict__ out, int n) {
    int i = blockIdx.x * 256 + threadIdx.x;
    if (i < n) out[i] = f2bf(in[i]);
}
__global__ __launch_bounds__(256) void transpose_kernel(const float* __restrict__ W,
                                                        ushort* __restrict__ Wt, int K, int N) {
    int idx = blockIdx.x * 256 + threadIdx.x;
    if (idx < K * N) {
        int k = idx / N, n = idx % N;
        Wt[n * K + k] = f2bf(W[idx]);
    }
}

// ---------- bf16 MFMA GEMM:  C[M,N] = A[M,K] @ Bt[N,K]^T  (128x128 tile) ----------
__global__ __launch_bounds__(256) void gemm_kernel(
    const ushort* __restrict__ A, const ushort* __restrict__ Bt,
    ushort* __restrict__ C, const float* __restrict__ bias,
    int M, int K, int N, int do_relu)
{
    __shared__ __align__(16) ushort Alds[128 * 32];
    __shared__ __align__(16) ushort Blds[128 * 32];
    const int t = threadIdx.x;
    const int w = t >> 6, l = t & 63;
    const int m0 = blockIdx.x * 128;
    const int n0 = blockIdx.y * 128;
    const int wr = (w >> 1) * 64, wc = (w & 1) * 64;
    const int lhi = l >> 4, llo = l & 15;

    floatx4 acc[4][4] = {};

    const int nkt = K >> 5;
    for (int kt = 0; kt < nkt; ++kt) {
        const int k0 = kt << 5;
#pragma unroll
        for (int i = 0; i < 2; ++i) {
            int s = i * 256 + t;
            int row = s >> 2, seg = s & 3;
            int gr = m0 + row; gr = gr < M ? gr : M - 1;   // clamp: never read past row M-1
            const ushort* ga = A + (size_t)gr * K + (k0 + seg * 8);
            __builtin_amdgcn_global_load_lds(
                (const __attribute__((address_space(1))) void*)ga,
                (__attribute__((address_space(3))) void*)(Alds + (size_t)(i * 256 + w * 64) * 8),
                16, 0, 0);
            const ushort* gb = Bt + (size_t)(n0 + row) * K + (k0 + seg * 8);
            __builtin_amdgcn_global_load_lds(
                (const __attribute__((address_space(1))) void*)gb,
                (__attribute__((address_space(3))) void*)(Blds + (size_t)(i * 256 + w * 64) * 8),
                16, 0, 0);
        }
        __syncthreads();
        short8 av[4], bv[4];
#pragma unroll
        for (int m = 0; m < 4; ++m)
            av[m] = *reinterpret_cast<const short8*>(&Alds[(wr + m * 16 + llo) * 32 + lhi * 8]);
#pragma unroll
        for (int n = 0; n < 4; ++n)
            bv[n] = *reinterpret_cast<const short8*>(&Blds[(wc + n * 16 + llo) * 32 + lhi * 8]);
#pragma unroll
        for (int m = 0; m < 4; ++m)
#pragma unroll
            for (int n = 0; n < 4; ++n)
                acc[m][n] = __builtin_amdgcn_mfma_f32_16x16x32_bf16(av[m], bv[n], acc[m][n], 0, 0, 0);
        __syncthreads();
    }

    const int lr = lhi * 4;
#pragma unroll
    for (int m = 0; m < 4; ++m) {
#pragma unroll
        for (int n = 0; n < 4; ++n) {
            int gcol = n0 + wc + n * 16 + llo;
            float badd = bias ? bias[gcol] : 0.0f;
#pragma unroll
            for (int j = 0; j < 4; ++j) {
                int grow = m0 + wr + m * 16 + lr + j;
                if (grow < M) {
                    float v = acc[m][n][j] + badd;
                    if (do_relu) v = fmaxf(v, 0.0f);
                    C[(size_t)grow * N + gcol] = f2bf(v);
                }
            }
        }
    }
}

// ---------- CSR gather + fused epilogue ----------
// out[node] = [relu]( sum_{s in adj(node)} h[s]*inv[s]*inv[node] + h[node]*inv[node]^2 [+ bias] )
// One wave per node; lane owns V=C/64 consecutive channels.
template<int C, bool RELU, bool BIAS, bool WF, bool WB>
__global__ __launch_bounds__(256) void gather_kernel(
    const int* __restrict__ row_ptr, const int* __restrict__ adj,
    const ushort* __restrict__ h, const float* __restrict__ invs,
    const float* __restrict__ bias,
    float* __restrict__ outF, ushort* __restrict__ outB)
{
    constexpr int V = C / 64;
    const int wv = threadIdx.x >> 6, l = threadIdx.x & 63;
    const int node = blockIdx.x * 4 + wv;
    if (node >= N_NODES) return;
    const int c0 = l * V;
    const int beg = row_ptr[node], end = row_ptr[node + 1];
    const float invd = invs[node];

    float acc[V];
#pragma unroll
    for (int k = 0; k < V; ++k) acc[k] = 0.0f;

    for (int e = beg; e < end; ++e) {
        const int s = adj[e];
        const float coef = invs[s] * invd;
        const ushort* hp = h + (size_t)s * C + c0;
        if constexpr (V == 4) {
            u16x4 hv = *reinterpret_cast<const u16x4*>(hp);
#pragma unroll
            for (int k = 0; k < 4; ++k) acc[k] += bf2f(hv[k]) * coef;
        } else {
            u16x8 hv = *reinterpret_cast<const u16x8*>(hp);
#pragma unroll
            for (int k = 0; k < 8; ++k) acc[k] += bf2f(hv[k]) * coef;
        }
    }
    {   // self-loop
        const float coef = invd * invd;
        const ushort* hp = h + (size_t)node * C + c0;
        if constexpr (V == 4) {
            u16x4 hv = *reinterpret_cast<const u16x4*>(hp);
#pragma unroll
            for (int k = 0; k < 4; ++k) acc[k] += bf2f(hv[k]) * coef;
        } else {
            u16x8 hv = *reinterpret_cast<const u16x8*>(hp);
#pragma unroll
            for (int k = 0; k < 8; ++k) acc[k] += bf2f(hv[k]) * coef;
        }
    }
#pragma unroll
    for (int k = 0; k < V; ++k) {
        float v = acc[k];
        if (BIAS) v += bias[c0 + k];
        if (RELU) v = fmaxf(v, 0.0f);
        acc[k] = v;
    }
    if (WF) {
        float* op = outF + (size_t)node * C + c0;
#pragma unroll
        for (int k = 0; k < V; k += 4)
            *reinterpret_cast<f32x4*>(op + k) = *reinterpret_cast<f32x4*>(&acc[k]);
    }
    if (WB) {
        ushort* op = outB + (size_t)node * C + c0;
        if constexpr (V == 4) {
            u16x4 o;
#pragma unroll
            for (int k = 0; k < 4; ++k) o[k] = f2bf(acc[k]);
            *reinterpret_cast<u16x4*>(op) = o;
        } else {
            u16x8 o;
#pragma unroll
            for (int k = 0; k < 8; ++k) o[k] = f2bf(acc[k]);
            *reinterpret_cast<u16x8*>(op) = o;
        }
    }
}

extern "C" void kernel_launch(void* const* d_in, const int* in_sizes, int n_in,
                              void* d_out, int out_size, void* d_ws, size_t ws_size,
                              hipStream_t stream)
{
    const float* x  = (const float*)d_in[0];
    const int* ei1  = (const int*)d_in[1];
    const int* ei2  = (const int*)d_in[2];
    const float* W1 = (const float*)d_in[3];
    const float* b1 = (const float*)d_in[4];
    const float* W2 = (const float*)d_in[5];
    const float* b2 = (const float*)d_in[6];
    const float* W3 = (const float*)d_in[7];
    const float* b3 = (const float*)d_in[8];
    const float* W4 = (const float*)d_in[9];
    const float* b4 = (const float*)d_in[10];
    float* z   = (float*)d_out;                        // [50000,256] f32
    float* z_g = z + (size_t)N_NODES * 256;            // [50000,256] f32

    const int E1 = in_sizes[1] / 2, E2 = in_sizes[2] / 2;
    const int* src1 = ei1;  const int* dst1 = ei1 + E1;
    const int* src2 = ei2;  const int* dst2 = ei2 + E2;

    // ---- aliases on d_out (each half = 51.2 MB = [50000,512] bf16 exactly) ----
    ushort* Xb = (ushort*)z;      // bf16 x; dead after GEMM1; then z f32 overwrites
    ushort* R1 = (ushort*)z_g;    // 512-wide bf16 ping buffer; final gather writes z_g f32 over it

    // ---- workspace (~57 MB) ----
    char* ws = (char*)d_ws;
    size_t off = 0;
    auto alloc = [&](size_t bytes) { void* p = ws + off; off += (bytes + 255) & ~(size_t)255; return p; };
    ushort* R0   = (ushort*)alloc((size_t)N_NODES * 512 * 2);
    float*  inv1 = (float*) alloc((size_t)N_NODES * 4);
    float*  inv2 = (float*) alloc((size_t)N_NODES * 4);
    int*    deg1 = (int*)   alloc((size_t)N_NODES * 4);
    int*    deg2 = (int*)   alloc((size_t)N_NODES * 4);
    int*    rp1  = (int*)   alloc((size_t)(N_NODES + 1) * 4);
    int*    rp2  = (int*)   alloc((size_t)(N_NODES + 1) * 4);
    int*    cur1 = (int*)   alloc((size_t)N_NODES * 4);
    int*    cur2 = (int*)   alloc((size_t)N_NODES * 4);
    int*    pre1 = (int*)   alloc((size_t)N_NODES * 4);
    int*    pre2 = (int*)   alloc((size_t)N_NODES * 4);
    int*    bs1  = (int*)   alloc(256 * 4);
    int*    bs2  = (int*)   alloc(256 * 4);
    int*    adj1 = (int*)   alloc((size_t)E1 * 4);
    int*    adj2 = (int*)   alloc((size_t)E2 * 4);
    ushort* Wt1  = (ushort*)alloc(512 * 512 * 2);
    ushort* Wt2  = (ushort*)alloc(256 * 512 * 2);
    ushort* Wt3  = (ushort*)alloc(512 * 256 * 2);
    ushort* Wt4  = (ushort*)alloc(256 * 512 * 2);

    const dim3 blk(256);
    const int MT = MP / 128;                 // 391 row tiles
    const int GB = (N_NODES + 3) / 4;        // gather blocks (4 waves each)
    const int NB = (N_NODES + 255) / 256;    // 196 scan blocks

    // ---- CSR build for both edge sets (hierarchical scan) ----
    hipMemsetAsync(deg1, 0, (size_t)N_NODES * 4, stream);
    hipMemsetAsync(deg2, 0, (size_t)N_NODES * 4, stream);
    deg_int_kernel<<<(E1 + 255) / 256, blk, 0, stream>>>(dst1, deg1, E1);
    deg_int_kernel<<<(E2 + 255) / 256, blk, 0, stream>>>(dst2, deg2, E2);
    inv_from_deg<<<(N_NODES + 255) / 256, blk, 0, stream>>>(deg1, inv1, N_NODES);
    inv_from_deg<<<(N_NODES + 255) / 256, blk, 0, stream>>>(deg2, inv2, N_NODES);
    scan1_kernel<<<NB, blk, 0, stream>>>(deg1, pre1, bs1, N_NODES);
    scan1_kernel<<<NB, blk, 0, stream>>>(deg2, pre2, bs2, N_NODES);
    scan2_kernel<<<1, blk, 0, stream>>>(bs1, NB, rp1 + N_NODES);
    scan2_kernel<<<1, blk, 0, stream>>>(bs2, NB, rp2 + N_NODES);
    scan3_kernel<<<NB, blk, 0, stream>>>(pre1, bs1, rp1, cur1, N_NODES);
    scan3_kernel<<<NB, blk, 0, stream>>>(pre2, bs2, rp2, cur2, N_NODES);
    fill_adj_kernel<<<(E1 + 255) / 256, blk, 0, stream>>>(src1, dst1, cur1, adj1, E1);
    fill_adj_kernel<<<(E2 + 255) / 256, blk, 0, stream>>>(src2, dst2, cur2, adj2, E2);

    // ---- weight prep + x -> bf16 ----
    transpose_kernel<<<(512 * 512 + 255) / 256, blk, 0, stream>>>(W1, Wt1, 512, 512);
    transpose_kernel<<<(512 * 256 + 255) / 256, blk, 0, stream>>>(W2, Wt2, 512, 256);
    transpose_kernel<<<(256 * 512 + 255) / 256, blk, 0, stream>>>(W3, Wt3, 256, 512);
    transpose_kernel<<<(512 * 256 + 255) / 256, blk, 0, stream>>>(W4, Wt4, 512, 256);
    f2b_kernel<<<(N_NODES * 512 + 255) / 256, blk, 0, stream>>>(x, Xb, N_NODES * 512);

    // ---- encoder 1, layer 1: h1 = x@W1 -> R0 ; a1 = relu(P1(h1)+b1) -> R1 (bf16) ----
    gemm_kernel<<<dim3(MT, 4), blk, 0, stream>>>(Xb, Wt1, R0, nullptr, N_NODES, 512, 512, 0);
    gather_kernel<512, true, true, false, true><<<GB, blk, 0, stream>>>(
        rp1, adj1, R0, inv1, b1, nullptr, R1);

    // ---- encoder 1, layer 2: h2 = a1@W2 -> R0(256) ; z = relu(P1(h2)+b2) -> z f32 + zb -> R1 ----
    gemm_kernel<<<dim3(MT, 2), blk, 0, stream>>>(R1, Wt2, R0, nullptr, N_NODES, 512, 256, 0);
    gather_kernel<256, true, true, true, true><<<GB, blk, 0, stream>>>(
        rp1, adj1, R0, inv1, b2, z, R1);

    // ---- encoder 2, layer 1 (propagate-first): pz = P2(zb) -> R0(256) ; a3 = relu(pz@W3+b3) -> R1 ----
    gather_kernel<256, false, false, false, true><<<GB, blk, 0, stream>>>(
        rp2, adj2, R1, inv2, nullptr, nullptr, R0);
    gemm_kernel<<<dim3(MT, 4), blk, 0, stream>>>(R0, Wt3, R1, b3, N_NODES, 256, 512, 1);

    // ---- encoder 2, layer 2: h4 = a3@W4 -> R0(256) ; z_g = relu(P2(h4)+b4) -> z_g f32 ----
    gemm_kernel<<<dim3(MT, 2), blk, 0, stream>>>(R1, Wt4, R0, nullptr, N_NODES, 512, 256, 0);
    gather_kernel<256, true, true, true, false><<<GB, blk, 0, stream>>>(
        rp2, adj2, R0, inv2, b4, z_g, nullptr);
}

// Round 6
// 585.874 us; speedup vs baseline: 3.5663x; 1.1450x over previous
//
#include <hip/hip_runtime.h>

#define N_NODES 50000
#define MP 50048            // row-tile padding (128-multiple) for GEMM grids

typedef short short8 __attribute__((ext_vector_type(8)));
typedef float floatx4 __attribute__((ext_vector_type(4)));
typedef ushort u16x4 __attribute__((ext_vector_type(4)));
typedef float f32x4 __attribute__((ext_vector_type(4)));

__device__ __forceinline__ float bf2f(ushort u) {
    union { unsigned int i; float f; } x; x.i = ((unsigned int)u) << 16; return x.f;
}
__device__ __forceinline__ ushort f2bf(float f) {
    union { float f; unsigned int i; } x; x.f = f;
    unsigned int r = x.i + 0x7FFFu + ((x.i >> 16) & 1u);
    return (ushort)(r >> 16);
}

// ---------- CSR build ----------
__global__ __launch_bounds__(256) void deg_int_kernel(const int* __restrict__ dst,
                                                      int* __restrict__ deg, int E) {
    int i = blockIdx.x * 256 + threadIdx.x;
    if (i < E) atomicAdd(&deg[dst[i]], 1);
}
__global__ __launch_bounds__(256) void inv_from_deg(const int* __restrict__ deg,
                                                    float* __restrict__ inv, int n) {
    int i = blockIdx.x * 256 + threadIdx.x;
    if (i < n) inv[i] = rsqrtf((float)deg[i] + 1.0f);
}

// ---- hierarchical exclusive scan (n <= 256*256) ----
__global__ __launch_bounds__(256) void scan1_kernel(const int* __restrict__ deg,
                                                    int* __restrict__ pre,
                                                    int* __restrict__ bsum, int n) {
    __shared__ int tmp[256];
    const int t = threadIdx.x;
    const int i = blockIdx.x * 256 + t;
    const int v = (i < n) ? deg[i] : 0;
    tmp[t] = v;
    __syncthreads();
#pragma unroll
    for (int d = 1; d < 256; d <<= 1) {
        int u = (t >= d) ? tmp[t - d] : 0;
        __syncthreads();
        tmp[t] += u;
        __syncthreads();
    }
    if (i < n) pre[i] = tmp[t] - v;           // exclusive within block
    if (t == 255) bsum[blockIdx.x] = tmp[255];
}
__global__ __launch_bounds__(256) void scan2_kernel(int* __restrict__ bsum, int nb,
                                                    int* __restrict__ row_ptr_n) {
    __shared__ int tmp[256];
    const int t = threadIdx.x;
    const int v = (t < nb) ? bsum[t] : 0;
    tmp[t] = v;
    __syncthreads();
#pragma unroll
    for (int d = 1; d < 256; d <<= 1) {
        int u = (t >= d) ? tmp[t - d] : 0;
        __syncthreads();
        tmp[t] += u;
        __syncthreads();
    }
    if (t < nb) bsum[t] = tmp[t] - v;         // exclusive block offsets
    if (t == 255) *row_ptr_n = tmp[255];      // grand total
}
__global__ __launch_bounds__(256) void scan3_kernel(const int* __restrict__ pre,
                                                    const int* __restrict__ bsum,
                                                    int* __restrict__ row_ptr,
                                                    int* __restrict__ cursor, int n) {
    const int i = blockIdx.x * 256 + threadIdx.x;
    if (i < n) {
        int v = pre[i] + bsum[blockIdx.x];
        row_ptr[i] = v;
        cursor[i] = v;
    }
}
// fill adjacency + per-edge source weight (invs[src]) in CSR order
__global__ __launch_bounds__(256) void fill_adj_kernel(const int* __restrict__ src,
                                                       const int* __restrict__ dst,
                                                       const float* __restrict__ invs,
                                                       int* __restrict__ cursor,
                                                       int* __restrict__ adj,
                                                       float* __restrict__ wgt, int E) {
    int i = blockIdx.x * 256 + threadIdx.x;
    if (i < E) {
        int s = src[i];
        int pos = atomicAdd(&cursor[dst[i]], 1);
        adj[pos] = s;
        wgt[pos] = invs[s];
    }
}

// ---------- weight prep ----------
__global__ __launch_bounds__(256) void f2b_kernel(const float* __restrict__ in,
                                                  ushort* __restrict__ out, int n) {
    int i = blockIdx.x * 256 + threadIdx.x;
    if (i < n) out[i] = f2bf(in[i]);
}
__global__ __launch_bounds__(256) void transpose_kernel(const float* __restrict__ W,
                                                        ushort* __restrict__ Wt, int K, int N) {
    int idx = blockIdx.x * 256 + threadIdx.x;
    if (idx < K * N) {
        int k = idx / N, n = idx % N;
        Wt[n * K + k] = f2bf(W[idx]);
    }
}

// ---------- bf16 MFMA GEMM:  C[M,N] = A[M,K] @ Bt[N,K]^T  (128x128 tile) ----------
__global__ __launch_bounds__(256) void gemm_kernel(
    const ushort* __restrict__ A, const ushort* __restrict__ Bt,
    ushort* __restrict__ C, const float* __restrict__ bias,
    int M, int K, int N, int do_relu)
{
    __shared__ __align__(16) ushort Alds[128 * 32];
    __shared__ __align__(16) ushort Blds[128 * 32];
    const int t = threadIdx.x;
    const int w = t >> 6, l = t & 63;
    const int m0 = blockIdx.x * 128;
    const int n0 = blockIdx.y * 128;
    const int wr = (w >> 1) * 64, wc = (w & 1) * 64;
    const int lhi = l >> 4, llo = l & 15;

    floatx4 acc[4][4] = {};

    const int nkt = K >> 5;
    for (int kt = 0; kt < nkt; ++kt) {
        const int k0 = kt << 5;
#pragma unroll
        for (int i = 0; i < 2; ++i) {
            int s = i * 256 + t;
            int row = s >> 2, seg = s & 3;
            int gr = m0 + row; gr = gr < M ? gr : M - 1;   // clamp: never read past row M-1
            const ushort* ga = A + (size_t)gr * K + (k0 + seg * 8);
            __builtin_amdgcn_global_load_lds(
                (const __attribute__((address_space(1))) void*)ga,
                (__attribute__((address_space(3))) void*)(Alds + (size_t)(i * 256 + w * 64) * 8),
                16, 0, 0);
            const ushort* gb = Bt + (size_t)(n0 + row) * K + (k0 + seg * 8);
            __builtin_amdgcn_global_load_lds(
                (const __attribute__((address_space(1))) void*)gb,
                (__attribute__((address_space(3))) void*)(Blds + (size_t)(i * 256 + w * 64) * 8),
                16, 0, 0);
        }
        __syncthreads();
        short8 av[4], bv[4];
#pragma unroll
        for (int m = 0; m < 4; ++m)
            av[m] = *reinterpret_cast<const short8*>(&Alds[(wr + m * 16 + llo) * 32 + lhi * 8]);
#pragma unroll
        for (int n = 0; n < 4; ++n)
            bv[n] = *reinterpret_cast<const short8*>(&Blds[(wc + n * 16 + llo) * 32 + lhi * 8]);
#pragma unroll
        for (int m = 0; m < 4; ++m)
#pragma unroll
            for (int n = 0; n < 4; ++n)
                acc[m][n] = __builtin_amdgcn_mfma_f32_16x16x32_bf16(av[m], bv[n], acc[m][n], 0, 0, 0);
        __syncthreads();
    }

    const int lr = lhi * 4;
#pragma unroll
    for (int m = 0; m < 4; ++m) {
#pragma unroll
        for (int n = 0; n < 4; ++n) {
            int gcol = n0 + wc + n * 16 + llo;
            float badd = bias ? bias[gcol] : 0.0f;
#pragma unroll
            for (int j = 0; j < 4; ++j) {
                int grow = m0 + wr + m * 16 + lr + j;
                if (grow < M) {
                    float v = acc[m][n][j] + badd;
                    if (do_relu) v = fmaxf(v, 0.0f);
                    C[(size_t)grow * N + gcol] = f2bf(v);
                }
            }
        }
    }
}

// ---------- CSR gather + fused epilogue ----------
// One wave per (node, 256-column block). Lane owns 4 consecutive channels.
// out[node] = [relu]( sum_e h[adj[e]]*wgt[e]*invd + h[node]*invd^2 [+ bias] )
template<bool RELU, bool BIAS, bool WF, bool WB>
__global__ __launch_bounds__(256) void gather_kernel(
    const int* __restrict__ row_ptr, const int* __restrict__ adj,
    const float* __restrict__ wgt,
    const ushort* __restrict__ h, int ldh,
    const float* __restrict__ invs, const float* __restrict__ bias,
    float* __restrict__ outF, ushort* __restrict__ outB, int ldo)
{
    const int wv = threadIdx.x >> 6, l = threadIdx.x & 63;
    const int node = blockIdx.x * 4 + wv;
    if (node >= N_NODES) return;
    const int c0 = blockIdx.y * 256 + l * 4;
    const int beg = row_ptr[node], end = row_ptr[node + 1];
    const float invd = invs[node];

    float a0[4] = {0.f, 0.f, 0.f, 0.f}, a1[4] = {0.f, 0.f, 0.f, 0.f};
    int e = beg;
    for (; e + 2 <= end; e += 2) {
        const int s0 = adj[e], s1 = adj[e + 1];
        const float w0 = wgt[e] * invd, w1 = wgt[e + 1] * invd;
        const u16x4 h0 = *reinterpret_cast<const u16x4*>(h + (size_t)s0 * ldh + c0);
        const u16x4 h1 = *reinterpret_cast<const u16x4*>(h + (size_t)s1 * ldh + c0);
#pragma unroll
        for (int k = 0; k < 4; ++k) {
            a0[k] += bf2f(h0[k]) * w0;
            a1[k] += bf2f(h1[k]) * w1;
        }
    }
    if (e < end) {
        const int s0 = adj[e];
        const float w0 = wgt[e] * invd;
        const u16x4 h0 = *reinterpret_cast<const u16x4*>(h + (size_t)s0 * ldh + c0);
#pragma unroll
        for (int k = 0; k < 4; ++k) a0[k] += bf2f(h0[k]) * w0;
    }
    {   // self-loop + merge
        const float ws = invd * invd;
        const u16x4 hs = *reinterpret_cast<const u16x4*>(h + (size_t)node * ldh + c0);
#pragma unroll
        for (int k = 0; k < 4; ++k) a0[k] += a1[k] + bf2f(hs[k]) * ws;
    }
#pragma unroll
    for (int k = 0; k < 4; ++k) {
        float v = a0[k];
        if (BIAS) v += bias[c0 + k];
        if (RELU) v = fmaxf(v, 0.0f);
        a0[k] = v;
    }
    if (WF)
        *reinterpret_cast<f32x4*>(outF + (size_t)node * ldo + c0) = *reinterpret_cast<f32x4*>(a0);
    if (WB) {
        u16x4 o;
#pragma unroll
        for (int k = 0; k < 4; ++k) o[k] = f2bf(a0[k]);
        *reinterpret_cast<u16x4*>(outB + (size_t)node * ldo + c0) = o;
    }
}

extern "C" void kernel_launch(void* const* d_in, const int* in_sizes, int n_in,
                              void* d_out, int out_size, void* d_ws, size_t ws_size,
                              hipStream_t stream)
{
    const float* x  = (const float*)d_in[0];
    const int* ei1  = (const int*)d_in[1];
    const int* ei2  = (const int*)d_in[2];
    const float* W1 = (const float*)d_in[3];
    const float* b1 = (const float*)d_in[4];
    const float* W2 = (const float*)d_in[5];
    const float* b2 = (const float*)d_in[6];
    const float* W3 = (const float*)d_in[7];
    const float* b3 = (const float*)d_in[8];
    const float* W4 = (const float*)d_in[9];
    const float* b4 = (const float*)d_in[10];
    float* z   = (float*)d_out;                        // [50000,256] f32
    float* z_g = z + (size_t)N_NODES * 256;            // [50000,256] f32

    const int E1 = in_sizes[1] / 2, E2 = in_sizes[2] / 2;
    const int* src1 = ei1;  const int* dst1 = ei1 + E1;
    const int* src2 = ei2;  const int* dst2 = ei2 + E2;

    // ---- aliases on d_out (each half = 51.2 MB = [50000,512] bf16 exactly) ----
    ushort* Xb = (ushort*)z;      // bf16 x; dead after GEMM1; then z f32 overwrites
    ushort* R1 = (ushort*)z_g;    // 512-wide bf16 ping buffer; final gather writes z_g f32 over it

    // ---- workspace (~61 MB) ----
    char* ws = (char*)d_ws;
    size_t off = 0;
    auto alloc = [&](size_t bytes) { void* p = ws + off; off += (bytes + 255) & ~(size_t)255; return p; };
    ushort* R0   = (ushort*)alloc((size_t)N_NODES * 512 * 2);
    float*  inv1 = (float*) alloc((size_t)N_NODES * 4);
    float*  inv2 = (float*) alloc((size_t)N_NODES * 4);
    int*    deg1 = (int*)   alloc((size_t)N_NODES * 4);
    int*    deg2 = (int*)   alloc((size_t)N_NODES * 4);
    int*    rp1  = (int*)   alloc((size_t)(N_NODES + 1) * 4);
    int*    rp2  = (int*)   alloc((size_t)(N_NODES + 1) * 4);
    int*    cur1 = (int*)   alloc((size_t)N_NODES * 4);
    int*    cur2 = (int*)   alloc((size_t)N_NODES * 4);
    int*    pre1 = (int*)   alloc((size_t)N_NODES * 4);
    int*    pre2 = (int*)   alloc((size_t)N_NODES * 4);
    int*    bs1  = (int*)   alloc(256 * 4);
    int*    bs2  = (int*)   alloc(256 * 4);
    int*    adj1 = (int*)   alloc((size_t)E1 * 4);
    int*    adj2 = (int*)   alloc((size_t)E2 * 4);
    float*  wgt1 = (float*) alloc((size_t)E1 * 4);
    float*  wgt2 = (float*) alloc((size_t)E2 * 4);
    ushort* Wt1  = (ushort*)alloc(512 * 512 * 2);
    ushort* Wt2  = (ushort*)alloc(256 * 512 * 2);
    ushort* Wt3  = (ushort*)alloc(512 * 256 * 2);
    ushort* Wt4  = (ushort*)alloc(256 * 512 * 2);

    const dim3 blk(256);
    const int MT = MP / 128;                 // 391 row tiles
    const int GB = (N_NODES + 3) / 4;        // gather blocks (4 waves each)
    const int NB = (N_NODES + 255) / 256;    // 196 scan blocks

    // ---- CSR build for both edge sets ----
    hipMemsetAsync(deg1, 0, (size_t)N_NODES * 4, stream);
    hipMemsetAsync(deg2, 0, (size_t)N_NODES * 4, stream);
    deg_int_kernel<<<(E1 + 255) / 256, blk, 0, stream>>>(dst1, deg1, E1);
    deg_int_kernel<<<(E2 + 255) / 256, blk, 0, stream>>>(dst2, deg2, E2);
    inv_from_deg<<<(N_NODES + 255) / 256, blk, 0, stream>>>(deg1, inv1, N_NODES);
    inv_from_deg<<<(N_NODES + 255) / 256, blk, 0, stream>>>(deg2, inv2, N_NODES);
    scan1_kernel<<<NB, blk, 0, stream>>>(deg1, pre1, bs1, N_NODES);
    scan1_kernel<<<NB, blk, 0, stream>>>(deg2, pre2, bs2, N_NODES);
    scan2_kernel<<<1, blk, 0, stream>>>(bs1, NB, rp1 + N_NODES);
    scan2_kernel<<<1, blk, 0, stream>>>(bs2, NB, rp2 + N_NODES);
    scan3_kernel<<<NB, blk, 0, stream>>>(pre1, bs1, rp1, cur1, N_NODES);
    scan3_kernel<<<NB, blk, 0, stream>>>(pre2, bs2, rp2, cur2, N_NODES);
    fill_adj_kernel<<<(E1 + 255) / 256, blk, 0, stream>>>(src1, dst1, inv1, cur1, adj1, wgt1, E1);
    fill_adj_kernel<<<(E2 + 255) / 256, blk, 0, stream>>>(src2, dst2, inv2, cur2, adj2, wgt2, E2);

    // ---- weight prep + x -> bf16 ----
    transpose_kernel<<<(512 * 512 + 255) / 256, blk, 0, stream>>>(W1, Wt1, 512, 512);
    transpose_kernel<<<(512 * 256 + 255) / 256, blk, 0, stream>>>(W2, Wt2, 512, 256);
    transpose_kernel<<<(256 * 512 + 255) / 256, blk, 0, stream>>>(W3, Wt3, 256, 512);
    transpose_kernel<<<(512 * 256 + 255) / 256, blk, 0, stream>>>(W4, Wt4, 512, 256);
    f2b_kernel<<<(N_NODES * 512 + 255) / 256, blk, 0, stream>>>(x, Xb, N_NODES * 512);

    // ---- encoder 1, layer 1: h1 = x@W1 -> R0 ; a1 = relu(P1(h1)+b1) -> R1 (bf16, 2 col-blocks) ----
    gemm_kernel<<<dim3(MT, 4), blk, 0, stream>>>(Xb, Wt1, R0, nullptr, N_NODES, 512, 512, 0);
    gather_kernel<true, true, false, true><<<dim3(GB, 2), blk, 0, stream>>>(
        rp1, adj1, wgt1, R0, 512, inv1, b1, nullptr, R1, 512);

    // ---- encoder 1, layer 2: h2 = a1@W2 -> R0(256) ; z = relu(P1(h2)+b2) -> z f32 + zb -> R1 ----
    gemm_kernel<<<dim3(MT, 2), blk, 0, stream>>>(R1, Wt2, R0, nullptr, N_NODES, 512, 256, 0);
    gather_kernel<true, true, true, true><<<dim3(GB, 1), blk, 0, stream>>>(
        rp1, adj1, wgt1, R0, 256, inv1, b2, z, R1, 256);

    // ---- encoder 2, layer 1 (propagate-first): pz = P2(zb) -> R0(256) ; a3 = relu(pz@W3+b3) -> R1 ----
    gather_kernel<false, false, false, true><<<dim3(GB, 1), blk, 0, stream>>>(
        rp2, adj2, wgt2, R1, 256, inv2, nullptr, nullptr, R0, 256);
    gemm_kernel<<<dim3(MT, 4), blk, 0, stream>>>(R0, Wt3, R1, b3, N_NODES, 256, 512, 1);

    // ---- encoder 2, layer 2: h4 = a3@W4 -> R0(256) ; z_g = relu(P2(h4)+b4) -> z_g f32 ----
    gemm_kernel<<<dim3(MT, 2), blk, 0, stream>>>(R1, Wt4, R0, nullptr, N_NODES, 512, 256, 0);
    gather_kernel<true, true, true, false><<<dim3(GB, 1), blk, 0, stream>>>(
        rp2, adj2, wgt2, R0, 256, inv2, b4, z_g, nullptr, 256);
}

// Round 7
// 513.571 us; speedup vs baseline: 4.0684x; 1.1408x over previous
//
#include <hip/hip_runtime.h>

#define N_NODES 50000
#define MP 50048            // row-tile padding (128-multiple) for GEMM grids

typedef short short8 __attribute__((ext_vector_type(8)));
typedef float floatx4 __attribute__((ext_vector_type(4)));
typedef ushort u16x4 __attribute__((ext_vector_type(4)));
typedef float f32x4 __attribute__((ext_vector_type(4)));

__device__ __forceinline__ float bf2f(ushort u) {
    union { unsigned int i; float f; } x; x.i = ((unsigned int)u) << 16; return x.f;
}
__device__ __forceinline__ ushort f2bf(float f) {
    union { float f; unsigned int i; } x; x.f = f;
    unsigned int r = x.i + 0x7FFFu + ((x.i >> 16) & 1u);
    return (ushort)(r >> 16);
}

// ---------- CSR build ----------
__global__ __launch_bounds__(256) void deg_int_kernel(const int* __restrict__ dst,
                                                      int* __restrict__ deg, int E) {
    int i = blockIdx.x * 256 + threadIdx.x;
    if (i < E) atomicAdd(&deg[dst[i]], 1);
}
__global__ __launch_bounds__(256) void inv_from_deg(const int* __restrict__ deg,
                                                    float* __restrict__ inv, int n) {
    int i = blockIdx.x * 256 + threadIdx.x;
    if (i < n) inv[i] = rsqrtf((float)deg[i] + 1.0f);
}

// ---- hierarchical exclusive scan (n <= 256*256) ----
__global__ __launch_bounds__(256) void scan1_kernel(const int* __restrict__ deg,
                                                    int* __restrict__ pre,
                                                    int* __restrict__ bsum, int n) {
    __shared__ int tmp[256];
    const int t = threadIdx.x;
    const int i = blockIdx.x * 256 + t;
    const int v = (i < n) ? deg[i] : 0;
    tmp[t] = v;
    __syncthreads();
#pragma unroll
    for (int d = 1; d < 256; d <<= 1) {
        int u = (t >= d) ? tmp[t - d] : 0;
        __syncthreads();
        tmp[t] += u;
        __syncthreads();
    }
    if (i < n) pre[i] = tmp[t] - v;           // exclusive within block
    if (t == 255) bsum[blockIdx.x] = tmp[255];
}
__global__ __launch_bounds__(256) void scan2_kernel(int* __restrict__ bsum, int nb,
                                                    int* __restrict__ row_ptr_n) {
    __shared__ int tmp[256];
    const int t = threadIdx.x;
    const int v = (t < nb) ? bsum[t] : 0;
    tmp[t] = v;
    __syncthreads();
#pragma unroll
    for (int d = 1; d < 256; d <<= 1) {
        int u = (t >= d) ? tmp[t - d] : 0;
        __syncthreads();
        tmp[t] += u;
        __syncthreads();
    }
    if (t < nb) bsum[t] = tmp[t] - v;         // exclusive block offsets
    if (t == 255) *row_ptr_n = tmp[255];      // grand total
}
__global__ __launch_bounds__(256) void scan3_kernel(const int* __restrict__ pre,
                                                    const int* __restrict__ bsum,
                                                    int* __restrict__ row_ptr,
                                                    int* __restrict__ cursor, int n) {
    const int i = blockIdx.x * 256 + threadIdx.x;
    if (i < n) {
        int v = pre[i] + bsum[blockIdx.x];
        row_ptr[i] = v;
        cursor[i] = v;
    }
}
// fill adjacency + per-edge source weight (invs[src]) in CSR order
__global__ __launch_bounds__(256) void fill_adj_kernel(const int* __restrict__ src,
                                                       const int* __restrict__ dst,
                                                       const float* __restrict__ invs,
                                                       int* __restrict__ cursor,
                                                       int* __restrict__ adj,
                                                       float* __restrict__ wgt, int E) {
    int i = blockIdx.x * 256 + threadIdx.x;
    if (i < E) {
        int s = src[i];
        int pos = atomicAdd(&cursor[dst[i]], 1);
        adj[pos] = s;
        wgt[pos] = invs[s];
    }
}

// ---------- weight prep ----------
__global__ __launch_bounds__(256) void f2b_kernel(const float* __restrict__ in,
                                                  ushort* __restrict__ out, int n) {
    int i = blockIdx.x * 256 + threadIdx.x;
    if (i < n) out[i] = f2bf(in[i]);
}
__global__ __launch_bounds__(256) void transpose_kernel(const float* __restrict__ W,
                                                        ushort* __restrict__ Wt, int K, int N) {
    int idx = blockIdx.x * 256 + threadIdx.x;
    if (idx < K * N) {
        int k = idx / N, n = idx % N;
        Wt[n * K + k] = f2bf(W[idx]);
    }
}

// ---------- bf16 MFMA GEMM:  C[M,N] = A[M,K] @ Bt[N,K]^T ----------
// 128x128 tile, 8 waves (512 thr), wave = 64x32 quadrant -> 32 AGPR acc.
// grid = (N/128, M/128): column-tiles of the same row-tile dispatch adjacently (L3 reuse of A).
__global__ __launch_bounds__(512, 4) void gemm_kernel(
    const ushort* __restrict__ A, const ushort* __restrict__ Bt,
    ushort* __restrict__ C, const float* __restrict__ bias,
    int M, int K, int N, int do_relu)
{
    __shared__ __align__(16) ushort Alds[128 * 32];
    __shared__ __align__(16) ushort Blds[128 * 32];
    const int t = threadIdx.x;
    const int w = t >> 6, l = t & 63;
    const int m0 = blockIdx.y * 128;
    const int n0 = blockIdx.x * 128;
    const int wr = (w >> 2) * 64, wc = (w & 3) * 32;
    const int lhi = l >> 4, llo = l & 15;

    floatx4 acc[4][2] = {};

    // staging: one global_load_lds per wave per buffer; dest = base + w*1024B + l*16B (lane-linear)
    const int srow = w * 16 + (l >> 2);      // 0..127
    const int scol = (l & 3) * 8;            // ushort offset within row
    int gr = m0 + srow; gr = gr < M ? gr : M - 1;
    const ushort* gA = A + (size_t)gr * K + scol;
    const ushort* gB = Bt + (size_t)(n0 + srow) * K + scol;
    ushort* lA = Alds + srow * 32 + scol;
    ushort* lB = Blds + srow * 32 + scol;

    const int nkt = K >> 5;
    for (int kt = 0; kt < nkt; ++kt) {
        const int k0 = kt << 5;
        __builtin_amdgcn_global_load_lds(
            (const __attribute__((address_space(1))) void*)(gA + k0),
            (__attribute__((address_space(3))) void*)lA, 16, 0, 0);
        __builtin_amdgcn_global_load_lds(
            (const __attribute__((address_space(1))) void*)(gB + k0),
            (__attribute__((address_space(3))) void*)lB, 16, 0, 0);
        __syncthreads();
        short8 av[4], bv[2];
#pragma unroll
        for (int m = 0; m < 4; ++m)
            av[m] = *reinterpret_cast<const short8*>(&Alds[(wr + m * 16 + llo) * 32 + lhi * 8]);
#pragma unroll
        for (int n = 0; n < 2; ++n)
            bv[n] = *reinterpret_cast<const short8*>(&Blds[(wc + n * 16 + llo) * 32 + lhi * 8]);
#pragma unroll
        for (int m = 0; m < 4; ++m)
#pragma unroll
            for (int n = 0; n < 2; ++n)
                acc[m][n] = __builtin_amdgcn_mfma_f32_16x16x32_bf16(av[m], bv[n], acc[m][n], 0, 0, 0);
        __syncthreads();
    }

    const int lr = lhi * 4;
#pragma unroll
    for (int m = 0; m < 4; ++m) {
#pragma unroll
        for (int n = 0; n < 2; ++n) {
            int gcol = n0 + wc + n * 16 + llo;
            float badd = bias ? bias[gcol] : 0.0f;
#pragma unroll
            for (int j = 0; j < 4; ++j) {
                int grow = m0 + wr + m * 16 + lr + j;
                if (grow < M) {
                    float v = acc[m][n][j] + badd;
                    if (do_relu) v = fmaxf(v, 0.0f);
                    C[(size_t)grow * N + gcol] = f2bf(v);
                }
            }
        }
    }
}

// ---------- CSR gather + fused epilogue ----------
// One wave per (node, 256-column block). Lane owns 4 consecutive channels.
template<bool RELU, bool BIAS, bool WF, bool WB>
__global__ __launch_bounds__(256) void gather_kernel(
    const int* __restrict__ row_ptr, const int* __restrict__ adj,
    const float* __restrict__ wgt,
    const ushort* __restrict__ h, int ldh,
    const float* __restrict__ invs, const float* __restrict__ bias,
    float* __restrict__ outF, ushort* __restrict__ outB, int ldo)
{
    const int wv = threadIdx.x >> 6, l = threadIdx.x & 63;
    const int node = blockIdx.x * 4 + wv;
    if (node >= N_NODES) return;
    const int c0 = blockIdx.y * 256 + l * 4;
    const int beg = row_ptr[node], end = row_ptr[node + 1];
    const float invd = invs[node];

    float a0[4] = {0.f, 0.f, 0.f, 0.f}, a1[4] = {0.f, 0.f, 0.f, 0.f};
    int e = beg;
    for (; e + 2 <= end; e += 2) {
        const int s0 = adj[e], s1 = adj[e + 1];
        const float w0 = wgt[e] * invd, w1 = wgt[e + 1] * invd;
        const u16x4 h0 = *reinterpret_cast<const u16x4*>(h + (size_t)s0 * ldh + c0);
        const u16x4 h1 = *reinterpret_cast<const u16x4*>(h + (size_t)s1 * ldh + c0);
#pragma unroll
        for (int k = 0; k < 4; ++k) {
            a0[k] += bf2f(h0[k]) * w0;
            a1[k] += bf2f(h1[k]) * w1;
        }
    }
    if (e < end) {
        const int s0 = adj[e];
        const float w0 = wgt[e] * invd;
        const u16x4 h0 = *reinterpret_cast<const u16x4*>(h + (size_t)s0 * ldh + c0);
#pragma unroll
        for (int k = 0; k < 4; ++k) a0[k] += bf2f(h0[k]) * w0;
    }
    {   // self-loop + merge
        const float ws = invd * invd;
        const u16x4 hs = *reinterpret_cast<const u16x4*>(h + (size_t)node * ldh + c0);
#pragma unroll
        for (int k = 0; k < 4; ++k) a0[k] += a1[k] + bf2f(hs[k]) * ws;
    }
#pragma unroll
    for (int k = 0; k < 4; ++k) {
        float v = a0[k];
        if (BIAS) v += bias[c0 + k];
        if (RELU) v = fmaxf(v, 0.0f);
        a0[k] = v;
    }
    if (WF)
        *reinterpret_cast<f32x4*>(outF + (size_t)node * ldo + c0) = *reinterpret_cast<f32x4*>(a0);
    if (WB) {
        u16x4 o;
#pragma unroll
        for (int k = 0; k < 4; ++k) o[k] = f2bf(a0[k]);
        *reinterpret_cast<u16x4*>(outB + (size_t)node * ldo + c0) = o;
    }
}

extern "C" void kernel_launch(void* const* d_in, const int* in_sizes, int n_in,
                              void* d_out, int out_size, void* d_ws, size_t ws_size,
                              hipStream_t stream)
{
    const float* x  = (const float*)d_in[0];
    const int* ei1  = (const int*)d_in[1];
    const int* ei2  = (const int*)d_in[2];
    const float* W1 = (const float*)d_in[3];
    const float* b1 = (const float*)d_in[4];
    const float* W2 = (const float*)d_in[5];
    const float* b2 = (const float*)d_in[6];
    const float* W3 = (const float*)d_in[7];
    const float* b3 = (const float*)d_in[8];
    const float* W4 = (const float*)d_in[9];
    const float* b4 = (const float*)d_in[10];
    float* z   = (float*)d_out;                        // [50000,256] f32
    float* z_g = z + (size_t)N_NODES * 256;            // [50000,256] f32

    const int E1 = in_sizes[1] / 2, E2 = in_sizes[2] / 2;
    const int* src1 = ei1;  const int* dst1 = ei1 + E1;
    const int* src2 = ei2;  const int* dst2 = ei2 + E2;

    // ---- aliases on d_out (each half = 51.2 MB = [50000,512] bf16 exactly) ----
    ushort* Xb = (ushort*)z;      // bf16 x; dead after GEMM1; then z f32 overwrites
    ushort* R1 = (ushort*)z_g;    // 512-wide bf16 ping buffer; final gather writes z_g f32 over it

    // ---- workspace (~61 MB) ----
    char* ws = (char*)d_ws;
    size_t off = 0;
    auto alloc = [&](size_t bytes) { void* p = ws + off; off += (bytes + 255) & ~(size_t)255; return p; };
    ushort* R0   = (ushort*)alloc((size_t)N_NODES * 512 * 2);
    float*  inv1 = (float*) alloc((size_t)N_NODES * 4);
    float*  inv2 = (float*) alloc((size_t)N_NODES * 4);
    int*    deg1 = (int*)   alloc((size_t)N_NODES * 4);
    int*    deg2 = (int*)   alloc((size_t)N_NODES * 4);
    int*    rp1  = (int*)   alloc((size_t)(N_NODES + 1) * 4);
    int*    rp2  = (int*)   alloc((size_t)(N_NODES + 1) * 4);
    int*    cur1 = (int*)   alloc((size_t)N_NODES * 4);
    int*    cur2 = (int*)   alloc((size_t)N_NODES * 4);
    int*    pre1 = (int*)   alloc((size_t)N_NODES * 4);
    int*    pre2 = (int*)   alloc((size_t)N_NODES * 4);
    int*    bs1  = (int*)   alloc(256 * 4);
    int*    bs2  = (int*)   alloc(256 * 4);
    int*    adj1 = (int*)   alloc((size_t)E1 * 4);
    int*    adj2 = (int*)   alloc((size_t)E2 * 4);
    float*  wgt1 = (float*) alloc((size_t)E1 * 4);
    float*  wgt2 = (float*) alloc((size_t)E2 * 4);
    ushort* Wt1  = (ushort*)alloc(512 * 512 * 2);
    ushort* Wt2  = (ushort*)alloc(256 * 512 * 2);
    ushort* Wt3  = (ushort*)alloc(512 * 256 * 2);
    ushort* Wt4  = (ushort*)alloc(256 * 512 * 2);

    const dim3 blk(256);
    const dim3 gblk(512);
    const int MT = MP / 128;                 // 391 row tiles
    const int GB = (N_NODES + 3) / 4;        // gather blocks (4 waves each)
    const int NB = (N_NODES + 255) / 256;    // 196 scan blocks

    // ---- CSR build for both edge sets ----
    hipMemsetAsync(deg1, 0, (size_t)N_NODES * 4, stream);
    hipMemsetAsync(deg2, 0, (size_t)N_NODES * 4, stream);
    deg_int_kernel<<<(E1 + 255) / 256, blk, 0, stream>>>(dst1, deg1, E1);
    deg_int_kernel<<<(E2 + 255) / 256, blk, 0, stream>>>(dst2, deg2, E2);
    inv_from_deg<<<(N_NODES + 255) / 256, blk, 0, stream>>>(deg1, inv1, N_NODES);
    inv_from_deg<<<(N_NODES + 255) / 256, blk, 0, stream>>>(deg2, inv2, N_NODES);
    scan1_kernel<<<NB, blk, 0, stream>>>(deg1, pre1, bs1, N_NODES);
    scan1_kernel<<<NB, blk, 0, stream>>>(deg2, pre2, bs2, N_NODES);
    scan2_kernel<<<1, blk, 0, stream>>>(bs1, NB, rp1 + N_NODES);
    scan2_kernel<<<1, blk, 0, stream>>>(bs2, NB, rp2 + N_NODES);
    scan3_kernel<<<NB, blk, 0, stream>>>(pre1, bs1, rp1, cur1, N_NODES);
    scan3_kernel<<<NB, blk, 0, stream>>>(pre2, bs2, rp2, cur2, N_NODES);
    fill_adj_kernel<<<(E1 + 255) / 256, blk, 0, stream>>>(src1, dst1, inv1, cur1, adj1, wgt1, E1);
    fill_adj_kernel<<<(E2 + 255) / 256, blk, 0, stream>>>(src2, dst2, inv2, cur2, adj2, wgt2, E2);

    // ---- weight prep + x -> bf16 ----
    transpose_kernel<<<(512 * 512 + 255) / 256, blk, 0, stream>>>(W1, Wt1, 512, 512);
    transpose_kernel<<<(512 * 256 + 255) / 256, blk, 0, stream>>>(W2, Wt2, 512, 256);
    transpose_kernel<<<(256 * 512 + 255) / 256, blk, 0, stream>>>(W3, Wt3, 256, 512);
    transpose_kernel<<<(512 * 256 + 255) / 256, blk, 0, stream>>>(W4, Wt4, 512, 256);
    f2b_kernel<<<(N_NODES * 512 + 255) / 256, blk, 0, stream>>>(x, Xb, N_NODES * 512);

    // ---- encoder 1, layer 1: h1 = x@W1 -> R0 ; a1 = relu(P1(h1)+b1) -> R1 (bf16, 2 col-blocks) ----
    gemm_kernel<<<dim3(4, MT), gblk, 0, stream>>>(Xb, Wt1, R0, nullptr, N_NODES, 512, 512, 0);
    gather_kernel<true, true, false, true><<<dim3(GB, 2), blk, 0, stream>>>(
        rp1, adj1, wgt1, R0, 512, inv1, b1, nullptr, R1, 512);

    // ---- encoder 1, layer 2: h2 = a1@W2 -> R0(256) ; z = relu(P1(h2)+b2) -> z f32 + zb -> R1 ----
    gemm_kernel<<<dim3(2, MT), gblk, 0, stream>>>(R1, Wt2, R0, nullptr, N_NODES, 512, 256, 0);
    gather_kernel<true, true, true, true><<<dim3(GB, 1), blk, 0, stream>>>(
        rp1, adj1, wgt1, R0, 256, inv1, b2, z, R1, 256);

    // ---- encoder 2, layer 1 (propagate-first): pz = P2(zb) -> R0(256) ; a3 = relu(pz@W3+b3) -> R1 ----
    gather_kernel<false, false, false, true><<<dim3(GB, 1), blk, 0, stream>>>(
        rp2, adj2, wgt2, R1, 256, inv2, nullptr, nullptr, R0, 256);
    gemm_kernel<<<dim3(4, MT), gblk, 0, stream>>>(R0, Wt3, R1, b3, N_NODES, 256, 512, 1);

    // ---- encoder 2, layer 2: h4 = a3@W4 -> R0(256) ; z_g = relu(P2(h4)+b4) -> z_g f32 ----
    gemm_kernel<<<dim3(2, MT), gblk, 0, stream>>>(R1, Wt4, R0, nullptr, N_NODES, 512, 256, 0);
    gather_kernel<true, true, true, false><<<dim3(GB, 1), blk, 0, stream>>>(
        rp2, adj2, wgt2, R0, 256, inv2, b4, z_g, nullptr, 256);
}

// Round 8
// 498.605 us; speedup vs baseline: 4.1905x; 1.0300x over previous
//
#include <hip/hip_runtime.h>

#define N_NODES 50000
#define MP 50048            // row-tile padding (128-multiple) for GEMM grids

typedef short short8 __attribute__((ext_vector_type(8)));
typedef float floatx4 __attribute__((ext_vector_type(4)));
typedef ushort u16x4 __attribute__((ext_vector_type(4)));
typedef float f32x4 __attribute__((ext_vector_type(4)));

__device__ __forceinline__ float bf2f(ushort u) {
    union { unsigned int i; float f; } x; x.i = ((unsigned int)u) << 16; return x.f;
}
__device__ __forceinline__ ushort f2bf(float f) {
    union { float f; unsigned int i; } x; x.f = f;
    unsigned int r = x.i + 0x7FFFu + ((x.i >> 16) & 1u);
    return (ushort)(r >> 16);
}

// ---------- CSR build ----------
__global__ __launch_bounds__(256) void deg_int_kernel(const int* __restrict__ dst,
                                                      int* __restrict__ deg, int E) {
    int i = blockIdx.x * 256 + threadIdx.x;
    if (i < E) atomicAdd(&deg[dst[i]], 1);
}
__global__ __launch_bounds__(256) void inv_from_deg(const int* __restrict__ deg,
                                                    float* __restrict__ inv, int n) {
    int i = blockIdx.x * 256 + threadIdx.x;
    if (i < n) inv[i] = rsqrtf((float)deg[i] + 1.0f);
}

// ---- hierarchical exclusive scan (n <= 256*256) ----
__global__ __launch_bounds__(256) void scan1_kernel(const int* __restrict__ deg,
                                                    int* __restrict__ pre,
                                                    int* __restrict__ bsum, int n) {
    __shared__ int tmp[256];
    const int t = threadIdx.x;
    const int i = blockIdx.x * 256 + t;
    const int v = (i < n) ? deg[i] : 0;
    tmp[t] = v;
    __syncthreads();
#pragma unroll
    for (int d = 1; d < 256; d <<= 1) {
        int u = (t >= d) ? tmp[t - d] : 0;
        __syncthreads();
        tmp[t] += u;
        __syncthreads();
    }
    if (i < n) pre[i] = tmp[t] - v;           // exclusive within block
    if (t == 255) bsum[blockIdx.x] = tmp[255];
}
__global__ __launch_bounds__(256) void scan2_kernel(int* __restrict__ bsum, int nb,
                                                    int* __restrict__ row_ptr_n) {
    __shared__ int tmp[256];
    const int t = threadIdx.x;
    const int v = (t < nb) ? bsum[t] : 0;
    tmp[t] = v;
    __syncthreads();
#pragma unroll
    for (int d = 1; d < 256; d <<= 1) {
        int u = (t >= d) ? tmp[t - d] : 0;
        __syncthreads();
        tmp[t] += u;
        __syncthreads();
    }
    if (t < nb) bsum[t] = tmp[t] - v;         // exclusive block offsets
    if (t == 255) *row_ptr_n = tmp[255];      // grand total
}
__global__ __launch_bounds__(256) void scan3_kernel(const int* __restrict__ pre,
                                                    const int* __restrict__ bsum,
                                                    int* __restrict__ row_ptr,
                                                    int* __restrict__ cursor, int n) {
    const int i = blockIdx.x * 256 + threadIdx.x;
    if (i < n) {
        int v = pre[i] + bsum[blockIdx.x];
        row_ptr[i] = v;
        cursor[i] = v;
    }
}
// fill adjacency + per-edge source weight (invs[src]) in CSR order
__global__ __launch_bounds__(256) void fill_adj_kernel(const int* __restrict__ src,
                                                       const int* __restrict__ dst,
                                                       const float* __restrict__ invs,
                                                       int* __restrict__ cursor,
                                                       int* __restrict__ adj,
                                                       float* __restrict__ wgt, int E) {
    int i = blockIdx.x * 256 + threadIdx.x;
    if (i < E) {
        int s = src[i];
        int pos = atomicAdd(&cursor[dst[i]], 1);
        adj[pos] = s;
        wgt[pos] = invs[s];
    }
}

// ---------- weight prep ----------
__global__ __launch_bounds__(256) void f2b_kernel(const float* __restrict__ in,
                                                  ushort* __restrict__ out, int n) {
    int i = blockIdx.x * 256 + threadIdx.x;
    if (i < n) out[i] = f2bf(in[i]);
}
__global__ __launch_bounds__(256) void transpose_kernel(const float* __restrict__ W,
                                                        ushort* __restrict__ Wt, int K, int N) {
    int idx = blockIdx.x * 256 + threadIdx.x;
    if (idx < K * N) {
        int k = idx / N, n = idx % N;
        Wt[n * K + k] = f2bf(W[idx]);
    }
}

// ---------- bf16 MFMA GEMM:  C[M,N] = A[M,K] @ Bt[N,K]^T ----------
// 128x128 tile, 8 waves (512 thr), wave = 64x32 quadrant -> 32 AGPR acc.
// grid = (N/128, M/128): column-tiles of the same row-tile dispatch adjacently (L3 reuse of A).
__global__ __launch_bounds__(512, 4) void gemm_kernel(
    const ushort* __restrict__ A, const ushort* __restrict__ Bt,
    ushort* __restrict__ C, const float* __restrict__ bias,
    int M, int K, int N, int do_relu)
{
    __shared__ __align__(16) ushort Alds[128 * 32];
    __shared__ __align__(16) ushort Blds[128 * 32];
    const int t = threadIdx.x;
    const int w = t >> 6, l = t & 63;
    const int m0 = blockIdx.y * 128;
    const int n0 = blockIdx.x * 128;
    const int wr = (w >> 2) * 64, wc = (w & 3) * 32;
    const int lhi = l >> 4, llo = l & 15;

    floatx4 acc[4][2] = {};

    // staging: one global_load_lds per wave per buffer; dest = base + w*1024B + l*16B (lane-linear)
    const int srow = w * 16 + (l >> 2);      // 0..127
    const int scol = (l & 3) * 8;            // ushort offset within row
    int gr = m0 + srow; gr = gr < M ? gr : M - 1;
    const ushort* gA = A + (size_t)gr * K + scol;
    const ushort* gB = Bt + (size_t)(n0 + srow) * K + scol;
    ushort* lA = Alds + srow * 32 + scol;
    ushort* lB = Blds + srow * 32 + scol;

    const int nkt = K >> 5;
    for (int kt = 0; kt < nkt; ++kt) {
        const int k0 = kt << 5;
        __builtin_amdgcn_global_load_lds(
            (const __attribute__((address_space(1))) void*)(gA + k0),
            (__attribute__((address_space(3))) void*)lA, 16, 0, 0);
        __builtin_amdgcn_global_load_lds(
            (const __attribute__((address_space(1))) void*)(gB + k0),
            (__attribute__((address_space(3))) void*)lB, 16, 0, 0);
        __syncthreads();
        short8 av[4], bv[2];
#pragma unroll
        for (int m = 0; m < 4; ++m)
            av[m] = *reinterpret_cast<const short8*>(&Alds[(wr + m * 16 + llo) * 32 + lhi * 8]);
#pragma unroll
        for (int n = 0; n < 2; ++n)
            bv[n] = *reinterpret_cast<const short8*>(&Blds[(wc + n * 16 + llo) * 32 + lhi * 8]);
#pragma unroll
        for (int m = 0; m < 4; ++m)
#pragma unroll
            for (int n = 0; n < 2; ++n)
                acc[m][n] = __builtin_amdgcn_mfma_f32_16x16x32_bf16(av[m], bv[n], acc[m][n], 0, 0, 0);
        __syncthreads();
    }

    const int lr = lhi * 4;
#pragma unroll
    for (int m = 0; m < 4; ++m) {
#pragma unroll
        for (int n = 0; n < 2; ++n) {
            int gcol = n0 + wc + n * 16 + llo;
            float badd = bias ? bias[gcol] : 0.0f;
#pragma unroll
            for (int j = 0; j < 4; ++j) {
                int grow = m0 + wr + m * 16 + lr + j;
                if (grow < M) {
                    float v = acc[m][n][j] + badd;
                    if (do_relu) v = fmaxf(v, 0.0f);
                    C[(size_t)grow * N + gcol] = f2bf(v);
                }
            }
        }
    }
}

// ---------- CSR gather + fused epilogue ----------
// One wave per (node, 256-column block). Lane owns 4 consecutive channels.
// Edge loop unrolled x4: 4 independent row loads in flight per wave.
template<bool RELU, bool BIAS, bool WF, bool WB>
__global__ __launch_bounds__(256) void gather_kernel(
    const int* __restrict__ row_ptr, const int* __restrict__ adj,
    const float* __restrict__ wgt,
    const ushort* __restrict__ h, int ldh,
    const float* __restrict__ invs, const float* __restrict__ bias,
    float* __restrict__ outF, ushort* __restrict__ outB, int ldo)
{
    const int wv = threadIdx.x >> 6, l = threadIdx.x & 63;
    const int node = blockIdx.x * 4 + wv;
    if (node >= N_NODES) return;
    const int c0 = blockIdx.y * 256 + l * 4;
    const int beg = row_ptr[node], end = row_ptr[node + 1];
    const float invd = invs[node];

    float a0[4] = {0.f,0.f,0.f,0.f}, a1[4] = {0.f,0.f,0.f,0.f};
    float a2[4] = {0.f,0.f,0.f,0.f}, a3[4] = {0.f,0.f,0.f,0.f};
    int e = beg;
    for (; e + 4 <= end; e += 4) {
        const int s0 = adj[e], s1 = adj[e+1], s2 = adj[e+2], s3 = adj[e+3];
        const float w0 = wgt[e] * invd, w1 = wgt[e+1] * invd;
        const float w2 = wgt[e+2] * invd, w3 = wgt[e+3] * invd;
        const u16x4 h0 = *reinterpret_cast<const u16x4*>(h + (size_t)s0 * ldh + c0);
        const u16x4 h1 = *reinterpret_cast<const u16x4*>(h + (size_t)s1 * ldh + c0);
        const u16x4 h2 = *reinterpret_cast<const u16x4*>(h + (size_t)s2 * ldh + c0);
        const u16x4 h3 = *reinterpret_cast<const u16x4*>(h + (size_t)s3 * ldh + c0);
#pragma unroll
        for (int k = 0; k < 4; ++k) {
            a0[k] += bf2f(h0[k]) * w0;
            a1[k] += bf2f(h1[k]) * w1;
            a2[k] += bf2f(h2[k]) * w2;
            a3[k] += bf2f(h3[k]) * w3;
        }
    }
    if (e + 2 <= end) {
        const int s0 = adj[e], s1 = adj[e+1];
        const float w0 = wgt[e] * invd, w1 = wgt[e+1] * invd;
        const u16x4 h0 = *reinterpret_cast<const u16x4*>(h + (size_t)s0 * ldh + c0);
        const u16x4 h1 = *reinterpret_cast<const u16x4*>(h + (size_t)s1 * ldh + c0);
#pragma unroll
        for (int k = 0; k < 4; ++k) {
            a0[k] += bf2f(h0[k]) * w0;
            a1[k] += bf2f(h1[k]) * w1;
        }
        e += 2;
    }
    if (e < end) {
        const int s0 = adj[e];
        const float w0 = wgt[e] * invd;
        const u16x4 h0 = *reinterpret_cast<const u16x4*>(h + (size_t)s0 * ldh + c0);
#pragma unroll
        for (int k = 0; k < 4; ++k) a0[k] += bf2f(h0[k]) * w0;
    }
    {   // self-loop + merge
        const float ws = invd * invd;
        const u16x4 hs = *reinterpret_cast<const u16x4*>(h + (size_t)node * ldh + c0);
#pragma unroll
        for (int k = 0; k < 4; ++k)
            a0[k] = (a0[k] + a1[k]) + (a2[k] + a3[k]) + bf2f(hs[k]) * ws;
    }
#pragma unroll
    for (int k = 0; k < 4; ++k) {
        float v = a0[k];
        if (BIAS) v += bias[c0 + k];
        if (RELU) v = fmaxf(v, 0.0f);
        a0[k] = v;
    }
    if (WF)
        *reinterpret_cast<f32x4*>(outF + (size_t)node * ldo + c0) = *reinterpret_cast<f32x4*>(a0);
    if (WB) {
        u16x4 o;
#pragma unroll
        for (int k = 0; k < 4; ++k) o[k] = f2bf(a0[k]);
        *reinterpret_cast<u16x4*>(outB + (size_t)node * ldo + c0) = o;
    }
}

extern "C" void kernel_launch(void* const* d_in, const int* in_sizes, int n_in,
                              void* d_out, int out_size, void* d_ws, size_t ws_size,
                              hipStream_t stream)
{
    const float* x  = (const float*)d_in[0];
    const int* ei1  = (const int*)d_in[1];
    const int* ei2  = (const int*)d_in[2];
    const float* W1 = (const float*)d_in[3];
    const float* b1 = (const float*)d_in[4];
    const float* W2 = (const float*)d_in[5];
    const float* b2 = (const float*)d_in[6];
    const float* W3 = (const float*)d_in[7];
    const float* b3 = (const float*)d_in[8];
    const float* W4 = (const float*)d_in[9];
    const float* b4 = (const float*)d_in[10];
    float* z   = (float*)d_out;                        // [50000,256] f32
    float* z_g = z + (size_t)N_NODES * 256;            // [50000,256] f32

    const int E1 = in_sizes[1] / 2, E2 = in_sizes[2] / 2;
    const int* src1 = ei1;  const int* dst1 = ei1 + E1;
    const int* src2 = ei2;  const int* dst2 = ei2 + E2;

    // ---- aliases on d_out (each half = 51.2 MB = [50000,512] bf16 exactly) ----
    ushort* Xb = (ushort*)z;      // bf16 x; dead after GEMM1; then z f32 overwrites
    ushort* R1 = (ushort*)z_g;    // 512-wide bf16 ping buffer; final gather writes z_g f32 over it

    // ---- workspace (~61 MB) ----
    char* ws = (char*)d_ws;
    size_t off = 0;
    auto alloc = [&](size_t bytes) { void* p = ws + off; off += (bytes + 255) & ~(size_t)255; return p; };
    ushort* R0   = (ushort*)alloc((size_t)N_NODES * 512 * 2);
    float*  inv1 = (float*) alloc((size_t)N_NODES * 4);
    float*  inv2 = (float*) alloc((size_t)N_NODES * 4);
    int*    deg1 = (int*)   alloc((size_t)N_NODES * 4);
    int*    deg2 = (int*)   alloc((size_t)N_NODES * 4);
    int*    rp1  = (int*)   alloc((size_t)(N_NODES + 1) * 4);
    int*    rp2  = (int*)   alloc((size_t)(N_NODES + 1) * 4);
    int*    cur1 = (int*)   alloc((size_t)N_NODES * 4);
    int*    cur2 = (int*)   alloc((size_t)N_NODES * 4);
    int*    pre1 = (int*)   alloc((size_t)N_NODES * 4);
    int*    pre2 = (int*)   alloc((size_t)N_NODES * 4);
    int*    bs1  = (int*)   alloc(256 * 4);
    int*    bs2  = (int*)   alloc(256 * 4);
    int*    adj1 = (int*)   alloc((size_t)E1 * 4);
    int*    adj2 = (int*)   alloc((size_t)E2 * 4);
    float*  wgt1 = (float*) alloc((size_t)E1 * 4);
    float*  wgt2 = (float*) alloc((size_t)E2 * 4);
    ushort* Wt1  = (ushort*)alloc(512 * 512 * 2);
    ushort* Wt2  = (ushort*)alloc(256 * 512 * 2);
    ushort* Wt3  = (ushort*)alloc(512 * 256 * 2);
    ushort* Wt4  = (ushort*)alloc(256 * 512 * 2);

    const dim3 blk(256);
    const dim3 gblk(512);
    const int MT = MP / 128;                 // 391 row tiles
    const int GB = (N_NODES + 3) / 4;        // gather blocks (4 waves each)
    const int NB = (N_NODES + 255) / 256;    // 196 scan blocks

    // ---- CSR build for both edge sets ----
    hipMemsetAsync(deg1, 0, (size_t)N_NODES * 4, stream);
    hipMemsetAsync(deg2, 0, (size_t)N_NODES * 4, stream);
    deg_int_kernel<<<(E1 + 255) / 256, blk, 0, stream>>>(dst1, deg1, E1);
    deg_int_kernel<<<(E2 + 255) / 256, blk, 0, stream>>>(dst2, deg2, E2);
    inv_from_deg<<<(N_NODES + 255) / 256, blk, 0, stream>>>(deg1, inv1, N_NODES);
    inv_from_deg<<<(N_NODES + 255) / 256, blk, 0, stream>>>(deg2, inv2, N_NODES);
    scan1_kernel<<<NB, blk, 0, stream>>>(deg1, pre1, bs1, N_NODES);
    scan1_kernel<<<NB, blk, 0, stream>>>(deg2, pre2, bs2, N_NODES);
    scan2_kernel<<<1, blk, 0, stream>>>(bs1, NB, rp1 + N_NODES);
    scan2_kernel<<<1, blk, 0, stream>>>(bs2, NB, rp2 + N_NODES);
    scan3_kernel<<<NB, blk, 0, stream>>>(pre1, bs1, rp1, cur1, N_NODES);
    scan3_kernel<<<NB, blk, 0, stream>>>(pre2, bs2, rp2, cur2, N_NODES);
    fill_adj_kernel<<<(E1 + 255) / 256, blk, 0, stream>>>(src1, dst1, inv1, cur1, adj1, wgt1, E1);
    fill_adj_kernel<<<(E2 + 255) / 256, blk, 0, stream>>>(src2, dst2, inv2, cur2, adj2, wgt2, E2);

    // ---- weight prep + x -> bf16 ----
    transpose_kernel<<<(512 * 512 + 255) / 256, blk, 0, stream>>>(W1, Wt1, 512, 512);
    transpose_kernel<<<(512 * 256 + 255) / 256, blk, 0, stream>>>(W2, Wt2, 512, 256);
    transpose_kernel<<<(256 * 512 + 255) / 256, blk, 0, stream>>>(W3, Wt3, 256, 512);
    transpose_kernel<<<(512 * 256 + 255) / 256, blk, 0, stream>>>(W4, Wt4, 512, 256);
    f2b_kernel<<<(N_NODES * 512 + 255) / 256, blk, 0, stream>>>(x, Xb, N_NODES * 512);

    // ---- encoder 1, layer 1: h1 = x@W1 -> R0 ; a1 = relu(P1(h1)+b1) -> R1 (bf16, 2 col-blocks) ----
    gemm_kernel<<<dim3(4, MT), gblk, 0, stream>>>(Xb, Wt1, R0, nullptr, N_NODES, 512, 512, 0);
    gather_kernel<true, true, false, true><<<dim3(GB, 2), blk, 0, stream>>>(
        rp1, adj1, wgt1, R0, 512, inv1, b1, nullptr, R1, 512);

    // ---- encoder 1, layer 2: h2 = a1@W2 -> R0(256) ; z = relu(P1(h2)+b2) -> z f32 + zb -> R1 ----
    gemm_kernel<<<dim3(2, MT), gblk, 0, stream>>>(R1, Wt2, R0, nullptr, N_NODES, 512, 256, 0);
    gather_kernel<true, true, true, true><<<dim3(GB, 1), blk, 0, stream>>>(
        rp1, adj1, wgt1, R0, 256, inv1, b2, z, R1, 256);

    // ---- encoder 2, layer 1 (propagate-first): pz = P2(zb) -> R0(256) ; a3 = relu(pz@W3+b3) -> R1 ----
    gather_kernel<false, false, false, true><<<dim3(GB, 1), blk, 0, stream>>>(
        rp2, adj2, wgt2, R1, 256, inv2, nullptr, nullptr, R0, 256);
    gemm_kernel<<<dim3(4, MT), gblk, 0, stream>>>(R0, Wt3, R1, b3, N_NODES, 256, 512, 1);

    // ---- encoder 2, layer 2: h4 = a3@W4 -> R0(256) ; z_g = relu(P2(h4)+b4) -> z_g f32 ----
    gemm_kernel<<<dim3(2, MT), gblk, 0, stream>>>(R1, Wt4, R0, nullptr, N_NODES, 512, 256, 0);
    gather_kernel<true, true, true, false><<<dim3(GB, 1), blk, 0, stream>>>(
        rp2, adj2, wgt2, R0, 256, inv2, b4, z_g, nullptr, 256);
}